// Round 16
// baseline (201.984 us; speedup 1.0000x reference)
//
#include <hip/hip_runtime.h>

#define Bsz 4
#define Nn 2048
#define Dd 256
#define Hh 4
#define HD 64
#define NTt 5
#define ETt 6
#define LOG2E 1.4426950408889634f
#define MSUB 24.0f
#define SCLQ 0.18033688011112042f   // 0.125 * LOG2E, folded into Q at qkv time

typedef float f32x4 __attribute__((ext_vector_type(4)));
typedef __bf16 bf16x8 __attribute__((ext_vector_type(8)));
typedef unsigned int u32x4 __attribute__((ext_vector_type(4)));
typedef unsigned int u32x2 __attribute__((ext_vector_type(2)));
typedef unsigned short u16;
typedef unsigned char u8;
typedef unsigned int uint;

static __device__ __forceinline__ u16 f2bf(float f) {
  unsigned int u = __builtin_bit_cast(unsigned int, f);
  u = (u + 0x7fffu + ((u >> 16) & 1u)) >> 16;
  return (u16)u;
}

static __device__ __forceinline__ bf16x8 ld8(const u16* p) {
  return __builtin_bit_cast(bf16x8, *(const u32x4*)p);
}

// async global->LDS, 16B per lane; LDS dest = wave-uniform base + lane*16
static __device__ __forceinline__ void stage16(const void* g, void* l) {
  __builtin_amdgcn_global_load_lds(
      (const __attribute__((address_space(1))) uint*)g,
      (__attribute__((address_space(3))) uint*)l, 16, 0, 0);
}

#define MFMA16(a, b, c) __builtin_amdgcn_mfma_f32_16x16x32_bf16((a), (b), (c), 0, 0, 0)

// ---------------- ws layout (bytes) ----------------
#define OFF_X      0u            // f32  [8192][256]        8388608
#define OFF_XBF    8388608u      // bf16 [8192][256]        4194304
#define OFF_WQKVT  12582912u     // bf16 [768][256]         393216
#define OFF_WOT    12976128u     // bf16 [256][256]         131072
#define OFF_BQKV   13107200u     // f32  [768]              3072
#define OFF_Q      13110272u     // bf16 [B,H,N,64]         4194304
#define OFF_K      17304576u     // bf16 [B,H,N,64]         4194304
#define OFF_VT     25693184u     // bf16 [B,H,64,N]         4194304
#define OFF_CTX    29887488u     // bf16 [8192][256]        4194304
#define OFF_CODES  34081792u     // u8   [B,128,32,64,16]   16777216

// ================= fused front: maskpack + embed + pack ===================
// blockIdx [0,512): maskpack  [512,2560): embed  [2560,3587): pack
__global__ __launch_bounds__(256) void front_kernel(
    const float* nodes, const int* node_types, const int* edge_types,
    const float* adjacency, const float* nte,
    const float* Wq, const float* Wk, const float* Wv, const float* Wo,
    const float* bq, const float* bk, const float* bv,
    float* xf, u16* xbf, u16* wqkvT, u16* woT, float* bqkv, u8* codes) {
  __shared__ uint lw[16 * 516 + 4];          // maskpack scratch (33KB)
  int gb = blockIdx.x;

  if (gb < 512) {
    // ---- maskpack: LDS-transposed, coalesced R/W ----
    int qt = gb & 127;
    int b = gb >> 7;
    int t = threadIdx.x;
    const int* ntb = node_types + b * Nn;
    const int* etb = edge_types + (size_t)b * Nn * Nn + (size_t)qt * 16 * Nn;
    const float* adjb = adjacency + (size_t)b * Nn * Nn + (size_t)qt * 16 * Nn;
#pragma unroll 4
    for (int a = 0; a < 32; ++a) {
      int idx = a * 256 + t;
      int row = idx >> 9;
      int k4 = idx & 511;
      int k0 = k4 * 4;
      int ntq = ntb[qt * 16 + row];
      int4 et4 = *(const int4*)(etb + (size_t)row * Nn + k0);
      float4 a4 = *(const float4*)(adjb + (size_t)row * Nn + k0);
      int4 nt4 = *(const int4*)(ntb + k0);
      int e[4] = {et4.x, et4.y, et4.z, et4.w};
      int n[4] = {nt4.x, nt4.y, nt4.z, nt4.w};
      float av[4] = {a4.x, a4.y, a4.z, a4.w};
      uint word = 0;
#pragma unroll
      for (int j = 0; j < 4; ++j) {
        int code = e[j] + ((ntq == n[j]) ? 6 : 0) + ((av[j] != 0.0f) ? 12 : 0);
        word |= (uint)(code * 4) << (8 * j);
      }
      lw[row * 516 + k4] = word;
    }
    __syncthreads();
    u8* rec = codes + (size_t)(b * 128 + qt) * 32768;
#pragma unroll
    for (int c = 0; c < 8; ++c) {
      int W = (c * 256 + t) * 4;
      int kt = W >> 8;
      int rem = W & 255;
      int l4 = rem >> 6;
      int l15 = (rem >> 2) & 15;
      int base = l15 * 516 + kt * 16 + l4;
      u32x4 o = {lw[base], lw[base + 4], lw[base + 8], lw[base + 12]};
      *(u32x4*)(rec + (size_t)W * 4) = o;
    }
  } else if (gb < 2560) {
    // ---- embed: x = nodes + node_type_embed[nt] ----
    int t = (gb - 512) * 256 + threadIdx.x;
    int flat = t * 4;
    int bn = flat >> 8, d0 = flat & 255;
    int nt = node_types[bn];
    float4 nv = *(const float4*)(nodes + flat);
    float4 ev = *(const float4*)(nte + nt * 256 + d0);
    float4 x4;
    x4.x = nv.x + ev.x; x4.y = nv.y + ev.y; x4.z = nv.z + ev.z; x4.w = nv.w + ev.w;
    *(float4*)(xf + flat) = x4;
    ushort4 xb;
    xb.x = f2bf(x4.x); xb.y = f2bf(x4.y); xb.z = f2bf(x4.z); xb.w = f2bf(x4.w);
    *(ushort4*)(xbf + flat) = xb;
  } else {
    // ---- pack weights (transposed, bf16) ----
    int tid = (gb - 2560) * 256 + threadIdx.x;
    if (tid < 196608) {
      int c = tid >> 8, k = tid & 255;
      int which = c >> 8, cc = c & 255;
      const float* W = (which == 0) ? Wq : ((which == 1) ? Wk : Wv);
      wqkvT[tid] = f2bf(W[k * 256 + cc]);
    } else if (tid < 262144) {
      int t2 = tid - 196608;
      int c = t2 >> 8, k = t2 & 255;
      woT[t2] = f2bf(Wo[k * 256 + c]);
    } else if (tid < 262912) {
      int c = tid - 262144;
      int which = c >> 8, cc = c & 255;
      bqkv[c] = (which == 0) ? bq[cc] : ((which == 1) ? bk[cc] : bv[cc]);
    }
  }
}

// ================= QKV GEMM v2: xbf read once, col-loop inside ============
// grid 128 row-blocks x 256 thr; A-fragments held in registers across the
// 12 column-blocks (weights stream from L1/L2). Q pre-scaled by SCLQ;
// V written transposed to Vtb[B,H,64,N].
__global__ __launch_bounds__(256) void qkv_kernel(const u16* xbf, const u16* wqkvT,
                                                  const float* bqkv,
                                                  u16* Qb, u16* Kb, u16* Vtb) {
  int rb = blockIdx.x;              // 0..127
  int w = threadIdx.x >> 6, lane = threadIdx.x & 63;
  int l15 = lane & 15, l4 = lane >> 4;
  int row0 = rb * 64 + w * 16;
  const u16* xr = xbf + (size_t)(row0 + l15) * 256;
  bf16x8 a[8];
#pragma unroll
  for (int kst = 0; kst < 8; ++kst) a[kst] = ld8(xr + kst * 32 + l4 * 8);

#pragma unroll 1
  for (int cb = 0; cb < 12; ++cb) {
    int col0 = cb * 64;
    f32x4 acc[4];
#pragma unroll
    for (int i = 0; i < 4; ++i) acc[i] = (f32x4){0.f, 0.f, 0.f, 0.f};
#pragma unroll
    for (int kst = 0; kst < 8; ++kst) {
      int k0 = kst * 32 + l4 * 8;
#pragma unroll
      for (int cs = 0; cs < 4; ++cs) {
        int col = col0 + cs * 16 + l15;
        bf16x8 bw = ld8(wqkvT + (size_t)col * 256 + k0);
        acc[cs] = MFMA16(a[kst], bw, acc[cs]);
      }
    }
#pragma unroll
    for (int cs = 0; cs < 4; ++cs) {
      int col = col0 + cs * 16 + l15;
      float bias = bqkv[col];
      int which = col >> 8, c = col & 255;
      int h = c >> 6, hd = c & 63;
      float scale = (which == 0) ? SCLQ : 1.0f;
#pragma unroll
      for (int j = 0; j < 4; ++j) {
        int row = row0 + l4 * 4 + j;
        int bb = row >> 11, n = row & 2047;
        u16 val = f2bf((acc[cs][j] + bias) * scale);
        if (which == 2)
          Vtb[((size_t)((bb * Hh + h) * HD + hd)) * Nn + n] = val;
        else if (which == 0)
          Qb[(size_t)(((bb * Hh + h) * Nn + n)) * HD + hd] = val;
        else
          Kb[(size_t)(((bb * Hh + h) * Nn + n)) * HD + hd] = val;
      }
    }
  }
}

// ================= attention: 8-wave k-split, 32-col tiles (R15) ==========
__global__ __launch_bounds__(512, 4) void attn_kernel(
    const u16* Qb, const u16* Kb, const u16* Vtb, const u8* codes,
    const float* ee_g, float* attn_out, u16* ctx_ws) {
  __shared__ __align__(16) char smem[81920];

  int bid0 = blockIdx.x;
  int bid = ((bid0 & 7) << 8) | (bid0 >> 3);   // XCD-chunked (2048 % 8 == 0)
  int qt = bid & 127;
  int h = (bid >> 7) & 3;
  int b = bid >> 9;
  int w = threadIdx.x >> 6, lane = threadIdx.x & 63;
  int l15 = lane & 15, l4 = lane >> 4;
  int q0 = qt * 16;
  int bh = b * Hh + h;
  int wk0 = w * 256;                 // this wave's k-range start

  float* lsh = (float*)(smem + 65536);
  char* pwave = smem + 65536 + w * 2048;
  char* kv0 = smem + w * 8192;
  char* kv1 = kv0 + 4096;

  // 24-entry bias LUT (log2 domain, MSUB folded in), one value per lane 0..23
  float lutv = 0.f;
  {
    int ln = lane;
    int et = ln - 6 * (ln / 6);
    int tm = (ln / 6) & 1;
    int adj = ln / 12;
    if (ln < 24)
      lutv = (ee_g[et * Hh + h] + (tm ? 0.10f : -0.05f)) * LOG2E +
             (adj ? 0.f : -1.442695041e9f) - MSUB;
  }
  int lut_i = __float_as_int(lutv);

  // Q as B-fragment (pre-scaled by SCLQ in qkv_kernel)
  const u16* Qp = Qb + (size_t)(bh * Nn + q0 + l15) * HD;
  bf16x8 bq0 = ld8(Qp + l4 * 8);
  bf16x8 bq1 = ld8(Qp + 32 + l4 * 8);

  const char* Kg = (const char*)Kb + (size_t)bh * Nn * 128 + (size_t)wk0 * 128;
  const char* KgS[4];
  {
    int colK = ((lane & 7) * 16) ^ (((lane >> 3) & 7) << 4);
#pragma unroll
    for (int j = 0; j < 4; ++j)
      KgS[j] = Kg + (size_t)(j * 8 + (lane >> 3)) * 128 + colK;
  }
  const char* Vg = (const char*)Vtb + (size_t)bh * HD * Nn * 2 + (size_t)wk0 * 2;
  const char* VgS[4];
  {
    int sV = (((lane & 3) ^ (lane >> 4)) & 3) * 16;
#pragma unroll
    for (int j = 0; j < 4; ++j)
      VgS[j] = Vg + (size_t)(j * 16 + (lane >> 2)) * (Nn * 2) + sV;
  }

  const char* cpb = (const char*)codes + (size_t)(b * 128 + qt) * 32768 +
                    (size_t)(w * 4) * 1024 + lane * 16;

  int swK = (l15 & 7) << 4;
  int raK = (l15 * 128 + l4 * 16) ^ swK;
  int rv = l15 * 64 + ((l4 ^ ((l15 >> 2) & 3)) * 16);

  uint p[8][4];
  float accl = 0.f;

  // ---------- pass 1: QK^T + bias + exp2, once ----------
  u32x2 cw = *(const u32x2*)cpb;
#pragma unroll
  for (int j = 0; j < 4; ++j) stage16(KgS[j], kv0 + j * 1024);

#pragma unroll
  for (int i = 0; i < 8; ++i) {
    u32x2 cwn = cw;
    char* kcur = (i & 1) ? kv1 : kv0;
    char* knxt = (i & 1) ? kv0 : kv1;
    if (i < 7) {
      cwn = *(const u32x2*)(cpb + ((i + 1) >> 1) * 1024 + ((i + 1) & 1) * 8);
#pragma unroll
      for (int j = 0; j < 4; ++j)
        stage16(KgS[j] + (size_t)(i + 1) * 4096, knxt + j * 1024);
    }
    __builtin_amdgcn_sched_barrier(0);
    if (i < 7) asm volatile("s_waitcnt vmcnt(5) lgkmcnt(0)" ::: "memory");
    else       asm volatile("s_waitcnt vmcnt(0) lgkmcnt(0)" ::: "memory");
    __builtin_amdgcn_sched_barrier(0);
#pragma unroll
    for (int ks = 0; ks < 2; ++ks) {
      uint cword = cw[ks];
      f32x4 acc;
#pragma unroll
      for (int j = 0; j < 4; ++j)
        acc[j] = __int_as_float(
            __builtin_amdgcn_ds_bpermute((int)((cword >> (8 * j)) & 0xFFu), lut_i));
      acc = MFMA16(ld8((const u16*)(kcur + raK + ks * 2048)), bq0, acc);
      acc = MFMA16(ld8((const u16*)(kcur + (raK ^ 64) + ks * 2048)), bq1, acc);
      float e0 = __builtin_amdgcn_exp2f(acc[0]);
      float e1 = __builtin_amdgcn_exp2f(acc[1]);
      float e2 = __builtin_amdgcn_exp2f(acc[2]);
      float e3 = __builtin_amdgcn_exp2f(acc[3]);
      accl += (e0 + e1) + (e2 + e3);
      asm("v_cvt_pk_bf16_f32 %0, %1, %2" : "=v"(p[i][ks * 2]) : "v"(e0), "v"(e1));
      asm("v_cvt_pk_bf16_f32 %0, %1, %2" : "=v"(p[i][ks * 2 + 1]) : "v"(e2), "v"(e3));
    }
    cw = cwn;
  }
  accl += __shfl_xor(accl, 16);
  accl += __shfl_xor(accl, 32);
  if (lane < 16) lsh[w * 16 + lane] = accl;
  __syncthreads();
  float tot = 0.f;
#pragma unroll
  for (int ww = 0; ww < 8; ++ww) tot += lsh[ww * 16 + l15];
  bool zrow = (tot == 0.0f);
  float cscale = zrow ? (1.0f / 2048.0f) : (1.0f / tot);
  __syncthreads();   // lsh read done before P writes overwrite its region

  // ---------- pass 2: attn store + PV (no QK recompute) ----------
  f32x4 ctx[4];
#pragma unroll
  for (int i = 0; i < 4; ++i) ctx[i] = (f32x4){0.f, 0.f, 0.f, 0.f};
  float* attb = attn_out + (size_t)bh * Nn * Nn + (size_t)(q0 + l15) * Nn + wk0;

#pragma unroll
  for (int j = 0; j < 4; ++j) stage16(VgS[j], kv0 + j * 1024);

#pragma unroll
  for (int i = 0; i < 8; ++i) {
    char* vcur = (i & 1) ? kv1 : kv0;
    char* vnxt = (i & 1) ? kv0 : kv1;
    if (i < 7) {
#pragma unroll
      for (int j = 0; j < 4; ++j)
        stage16(VgS[j] + (size_t)(i + 1) * 64, vnxt + j * 1024);
    }
    __builtin_amdgcn_sched_barrier(0);
    if (i == 0)     asm volatile("s_waitcnt vmcnt(4) lgkmcnt(0)" ::: "memory");
    else if (i < 7) asm volatile("s_waitcnt vmcnt(6) lgkmcnt(0)" ::: "memory");
    else            asm volatile("s_waitcnt vmcnt(2) lgkmcnt(0)" ::: "memory");
    __builtin_amdgcn_sched_barrier(0);

    uint pp[4];
#pragma unroll
    for (int r = 0; r < 4; ++r) pp[r] = zrow ? 0x3F803F80u : p[i][r];
    // P -> LDS (swizzled 64B rows)
#pragma unroll
    for (int ks = 0; ks < 2; ++ks) {
      int slot = (ks * 2 + (l4 >> 1)) ^ ((l15 >> 2) & 3);
      int2 wv = {(int)pp[ks * 2], (int)pp[ks * 2 + 1]};
      *(int2*)(pwave + l15 * 64 + slot * 16 + (l4 & 1) * 8) = wv;
    }
    // attn output: float(p)*cscale
#pragma unroll
    for (int ks = 0; ks < 2; ++ks) {
      uint u0 = pp[ks * 2], u1 = pp[ks * 2 + 1];
      f32x4 o;
      o[0] = __int_as_float((int)(u0 << 16)) * cscale;
      o[1] = __int_as_float((int)(u0 & 0xFFFF0000u)) * cscale;
      o[2] = __int_as_float((int)(u1 << 16)) * cscale;
      o[3] = __int_as_float((int)(u1 & 0xFFFF0000u)) * cscale;
      __builtin_nontemporal_store(o, (f32x4*)(attb + i * 32 + ks * 16 + l4 * 4));
    }
    // PV with unnormalized P
    bf16x8 pa = ld8((const u16*)(pwave + rv));
#pragma unroll
    for (int d = 0; d < 4; ++d) {
      bf16x8 v = ld8((const u16*)(vcur + d * 1024 + rv));
      ctx[d] = MFMA16(pa, v, ctx[d]);
    }
  }

  // per-row scale of partial ctx (rows = l4*4+j; cscale lives at lane==row)
  float csr[4];
#pragma unroll
  for (int j = 0; j < 4; ++j)
    csr[j] = __int_as_float(
        __builtin_amdgcn_ds_bpermute((l4 * 4 + j) * 4, __float_as_int(cscale)));
#pragma unroll
  for (int d = 0; d < 4; ++d)
#pragma unroll
    for (int j = 0; j < 4; ++j) ctx[d][j] *= csr[j];

  // combine partial ctx across the 8 k-split waves (reuse K/V region)
  __syncthreads();
  float* creg = (float*)smem;
  if (w > 0) {
    float* cs_ = creg + ((size_t)(w - 1) * 64 + lane) * 17;
#pragma unroll
    for (int d = 0; d < 4; ++d)
#pragma unroll
      for (int j = 0; j < 4; ++j) cs_[d * 4 + j] = ctx[d][j];
  }
  __syncthreads();
  if (w == 0) {
#pragma unroll
    for (int d = 0; d < 4; ++d) {
      int col = h * 64 + d * 16 + l15;
#pragma unroll
      for (int j = 0; j < 4; ++j) {
        float v = ctx[d][j];
#pragma unroll
        for (int ww = 0; ww < 7; ++ww)
          v += creg[((size_t)ww * 64 + lane) * 17 + d * 4 + j];
        int qrow = q0 + l4 * 4 + j;
        ctx_ws[(size_t)(b * Nn + qrow) * Dd + col] = f2bf(v);
      }
    }
  }
}

// ================= out GEMM + residual + LayerNorm =================
__global__ __launch_bounds__(256) void outln_kernel(const u16* ctxb, const u16* woT,
                                                    const float* bo, const float* xf,
                                                    const float* ln_g, const float* ln_b,
                                                    float* yout) {
  __shared__ float ytile[32][257];
  __shared__ float muS[32], rvS[32];
  int bm0 = blockIdx.x * 32;
  int w = threadIdx.x >> 6, lane = threadIdx.x & 63;
  int l15 = lane & 15, l4 = lane >> 4;
  f32x4 acc[2][4];
#pragma unroll
  for (int q = 0; q < 2; ++q)
#pragma unroll
    for (int i = 0; i < 4; ++i) acc[q][i] = (f32x4){0.f, 0.f, 0.f, 0.f};
#pragma unroll
  for (int kst = 0; kst < 8; ++kst) {
    int k0 = kst * 32 + l4 * 8;
    bf16x8 a0 = ld8(ctxb + (size_t)(bm0 + l15) * 256 + k0);
    bf16x8 a1 = ld8(ctxb + (size_t)(bm0 + 16 + l15) * 256 + k0);
#pragma unroll
    for (int ds_ = 0; ds_ < 4; ++ds_) {
      bf16x8 bw = ld8(woT + (size_t)(w * 64 + ds_ * 16 + l15) * 256 + k0);
      acc[0][ds_] = MFMA16(a0, bw, acc[0][ds_]);
      acc[1][ds_] = MFMA16(a1, bw, acc[1][ds_]);
    }
  }
#pragma unroll
  for (int qs = 0; qs < 2; ++qs)
#pragma unroll
    for (int ds_ = 0; ds_ < 4; ++ds_) {
      int col = w * 64 + ds_ * 16 + l15;
      float bof = bo[col];
#pragma unroll
      for (int j = 0; j < 4; ++j) {
        int row = qs * 16 + l4 * 4 + j;
        ytile[row][col] = acc[qs][ds_][j] + bof + xf[(size_t)(bm0 + row) * 256 + col];
      }
    }
  __syncthreads();
  int row = threadIdx.x >> 3, seg = threadIdx.x & 7;
  float ps = 0.f, pq = 0.f;
#pragma unroll
  for (int c = 0; c < 32; ++c) {
    float v = ytile[row][seg * 32 + c];
    ps += v; pq += v * v;
  }
  ps += __shfl_xor(ps, 1); pq += __shfl_xor(pq, 1);
  ps += __shfl_xor(ps, 2); pq += __shfl_xor(pq, 2);
  ps += __shfl_xor(ps, 4); pq += __shfl_xor(pq, 4);
  if (seg == 0) {
    float mu = ps * (1.0f / 256.0f);
    muS[row] = mu;
    rvS[row] = rsqrtf(pq * (1.0f / 256.0f) - mu * mu + 1e-5f);
  }
  __syncthreads();
  float mu = muS[row], rv = rvS[row];
  float* yr = yout + (size_t)(bm0 + row) * 256;
#pragma unroll
  for (int c0 = 0; c0 < 32; c0 += 4) {
    int c = seg * 32 + c0;
    float4 o;
    o.x = (ytile[row][c + 0] - mu) * rv * ln_g[c + 0] + ln_b[c + 0];
    o.y = (ytile[row][c + 1] - mu) * rv * ln_g[c + 1] + ln_b[c + 1];
    o.z = (ytile[row][c + 2] - mu) * rv * ln_g[c + 2] + ln_b[c + 2];
    o.w = (ytile[row][c + 3] - mu) * rv * ln_g[c + 3] + ln_b[c + 3];
    *(float4*)(yr + c) = o;
  }
}

extern "C" void kernel_launch(void* const* d_in, const int* in_sizes, int n_in,
                              void* d_out, int out_size, void* d_ws, size_t ws_size,
                              hipStream_t stream) {
  const float* nodes = (const float*)d_in[0];
  const int* node_types = (const int*)d_in[1];
  const int* edge_types = (const int*)d_in[2];
  const float* adjacency = (const float*)d_in[3];
  const float* nte = (const float*)d_in[4];
  const float* ee = (const float*)d_in[5];
  const float* Wq = (const float*)d_in[6];
  const float* bq = (const float*)d_in[7];
  const float* Wk = (const float*)d_in[8];
  const float* bk = (const float*)d_in[9];
  const float* Wv = (const float*)d_in[10];
  const float* bv = (const float*)d_in[11];
  const float* Wo = (const float*)d_in[12];
  const float* bo = (const float*)d_in[13];
  const float* ln_g = (const float*)d_in[14];
  const float* ln_b = (const float*)d_in[15];

  float* y = (float*)d_out;
  float* attn = y + (size_t)Bsz * Nn * Dd;

  char* ws = (char*)d_ws;
  float* xf = (float*)(ws + OFF_X);
  u16* xbf = (u16*)(ws + OFF_XBF);
  u16* wqkvT = (u16*)(ws + OFF_WQKVT);
  u16* woT = (u16*)(ws + OFF_WOT);
  float* bqkv = (float*)(ws + OFF_BQKV);
  u16* Qb = (u16*)(ws + OFF_Q);
  u16* Kb = (u16*)(ws + OFF_K);
  u16* Vtb = (u16*)(ws + OFF_VT);
  u16* ctxb = (u16*)(ws + OFF_CTX);
  u8* codes = (u8*)(ws + OFF_CODES);

  front_kernel<<<3587, 256, 0, stream>>>(nodes, node_types, edge_types, adjacency,
                                         nte, Wq, Wk, Wv, Wo, bq, bk, bv,
                                         xf, xbf, wqkvT, woT, bqkv, codes);
  qkv_kernel<<<128, 256, 0, stream>>>(xbf, wqkvT, bqkv, Qb, Kb, Vtb);
  attn_kernel<<<2048, 512, 0, stream>>>(Qb, Kb, Vtb, codes, ee, attn, ctxb);
  outln_kernel<<<256, 256, 0, stream>>>(ctxb, woT, bo, xf, ln_g, ln_b, y);
}

// Round 17
// 197.481 us; speedup vs baseline: 1.0228x; 1.0228x over previous
//
#include <hip/hip_runtime.h>

#define Bsz 4
#define Nn 2048
#define Dd 256
#define Hh 4
#define HD 64
#define NTt 5
#define ETt 6
#define LOG2E 1.4426950408889634f
#define MSUB 24.0f
#define SCLQ 0.18033688011112042f   // 0.125 * LOG2E, folded into Q at qkv time

typedef float f32x4 __attribute__((ext_vector_type(4)));
typedef __bf16 bf16x8 __attribute__((ext_vector_type(8)));
typedef unsigned int u32x4 __attribute__((ext_vector_type(4)));
typedef unsigned int u32x2 __attribute__((ext_vector_type(2)));
typedef unsigned short u16;
typedef unsigned char u8;
typedef unsigned int uint;

static __device__ __forceinline__ u16 f2bf(float f) {
  unsigned int u = __builtin_bit_cast(unsigned int, f);
  u = (u + 0x7fffu + ((u >> 16) & 1u)) >> 16;
  return (u16)u;
}

static __device__ __forceinline__ bf16x8 ld8(const u16* p) {
  return __builtin_bit_cast(bf16x8, *(const u32x4*)p);
}

// async global->LDS, 16B per lane; LDS dest = wave-uniform base + lane*16
static __device__ __forceinline__ void stage16(const void* g, void* l) {
  __builtin_amdgcn_global_load_lds(
      (const __attribute__((address_space(1))) uint*)g,
      (__attribute__((address_space(3))) uint*)l, 16, 0, 0);
}

#define MFMA16(a, b, c) __builtin_amdgcn_mfma_f32_16x16x32_bf16((a), (b), (c), 0, 0, 0)

// ---------------- ws layout (bytes) ----------------
#define OFF_X      0u            // f32  [8192][256]        8388608
#define OFF_XBF    8388608u      // bf16 [8192][256]        4194304
#define OFF_WQKVT  12582912u     // bf16 [768][256]         393216
#define OFF_WOT    12976128u     // bf16 [256][256]         131072
#define OFF_BQKV   13107200u     // f32  [768]              3072
#define OFF_Q      13110272u     // bf16 [B,H,N,64]         4194304
#define OFF_K      17304576u     // bf16 [B,H,N,64]         4194304
#define OFF_VT     25693184u     // bf16 [B,H,64,N]         4194304
#define OFF_CTX    29887488u     // bf16 [8192][256]        4194304
#define OFF_CODES  34081792u     // u8   [B,128,32,64,16]   16777216

// ================= pack weights (transposed, bf16) =================
__global__ void pack_kernel(const float* Wq, const float* Wk, const float* Wv,
                            const float* Wo, const float* bq, const float* bk,
                            const float* bv, u16* wqkvT, u16* woT, float* bqkv) {
  int tid = blockIdx.x * 256 + threadIdx.x;
  if (tid < 196608) {                 // WqkvT[c][k] = W_which[k][cc]
    int c = tid >> 8, k = tid & 255;
    int which = c >> 8, cc = c & 255;
    const float* W = (which == 0) ? Wq : ((which == 1) ? Wk : Wv);
    wqkvT[tid] = f2bf(W[k * 256 + cc]);
  } else if (tid < 262144) {          // WoT[c][k] = Wo[k][c]
    int t2 = tid - 196608;
    int c = t2 >> 8, k = t2 & 255;
    woT[t2] = f2bf(Wo[k * 256 + c]);
  } else if (tid < 262912) {
    int c = tid - 262144;
    int which = c >> 8, cc = c & 255;
    bqkv[c] = (which == 0) ? bq[cc] : ((which == 1) ? bk[cc] : bv[cc]);
  }
}

// ================= x = nodes + node_type_embed[nt] =================
__global__ void embed_kernel(const float* nodes, const int* node_types,
                             const float* nte, float* xf, u16* xbf) {
  int t = blockIdx.x * 256 + threadIdx.x;    // 524288 threads, 4 floats each
  int flat = t * 4;
  int bn = flat >> 8, d0 = flat & 255;
  int nt = node_types[bn];
  float4 nv = *(const float4*)(nodes + flat);
  float4 ev = *(const float4*)(nte + nt * 256 + d0);
  float4 x4;
  x4.x = nv.x + ev.x; x4.y = nv.y + ev.y; x4.z = nv.z + ev.z; x4.w = nv.w + ev.w;
  *(float4*)(xf + flat) = x4;
  ushort4 xb;
  xb.x = f2bf(x4.x); xb.y = f2bf(x4.y); xb.z = f2bf(x4.z); xb.w = f2bf(x4.w);
  *(ushort4*)(xbf + flat) = xb;
}

// ================= mask pack v2: LDS-transposed, coalesced R/W ============
__global__ __launch_bounds__(256) void maskpack_kernel(
    const int* node_types, const int* edge_types, const float* adjacency,
    u8* codes) {
  __shared__ uint lw[16 * 516 + 4];          // padded stride 516 (33KB)
  int blk = blockIdx.x;                       // 0..511
  int qt = blk & 127;
  int b = blk >> 7;
  int t = threadIdx.x;
  const int* ntb = node_types + b * Nn;
  const int* etb = edge_types + (size_t)b * Nn * Nn + (size_t)qt * 16 * Nn;
  const float* adjb = adjacency + (size_t)b * Nn * Nn + (size_t)qt * 16 * Nn;

#pragma unroll 4
  for (int a = 0; a < 32; ++a) {
    int idx = a * 256 + t;                    // int4 index within (16 x 512)
    int row = idx >> 9;                       // 0..15
    int k4 = idx & 511;                       // int4 within row
    int k0 = k4 * 4;
    int ntq = ntb[qt * 16 + row];
    int4 et4 = *(const int4*)(etb + (size_t)row * Nn + k0);
    float4 a4 = *(const float4*)(adjb + (size_t)row * Nn + k0);
    int4 nt4 = *(const int4*)(ntb + k0);
    int e[4] = {et4.x, et4.y, et4.z, et4.w};
    int n[4] = {nt4.x, nt4.y, nt4.z, nt4.w};
    float av[4] = {a4.x, a4.y, a4.z, a4.w};
    uint word = 0;
#pragma unroll
    for (int j = 0; j < 4; ++j) {
      int code = e[j] + ((ntq == n[j]) ? 6 : 0) + ((av[j] != 0.0f) ? 12 : 0);
      word |= (uint)(code * 4) << (8 * j);
    }
    lw[row * 516 + k4] = word;
  }
  __syncthreads();

  u8* rec = codes + (size_t)(b * 128 + qt) * 32768;
#pragma unroll
  for (int c = 0; c < 8; ++c) {
    int W = (c * 256 + t) * 4;                // output word base (dwordx4)
    int kt = W >> 8;
    int rem = W & 255;
    int l4 = rem >> 6;
    int l15 = (rem >> 2) & 15;
    int base = l15 * 516 + kt * 16 + l4;      // + 4*s for s=0..3 (ks)
    u32x4 o = {lw[base], lw[base + 4], lw[base + 8], lw[base + 12]};
    *(u32x4*)(rec + (size_t)W * 4) = o;
  }
}

// ================= QKV GEMM: [8192,256] @ [256,768] =================
__global__ __launch_bounds__(256) void qkv_kernel(const u16* xbf, const u16* wqkvT,
                                                  const float* bqkv,
                                                  u16* Qb, u16* Kb, u16* Vtb) {
  int cb = blockIdx.x;              // 0..11
  int rb = blockIdx.y;              // 0..127
  int w = threadIdx.x >> 6, lane = threadIdx.x & 63;
  int l15 = lane & 15, l4 = lane >> 4;
  int row0 = rb * 64 + w * 16;
  int col0 = cb * 64;
  const u16* xr = xbf + (size_t)(row0 + l15) * 256;
  f32x4 acc[4];
#pragma unroll
  for (int i = 0; i < 4; ++i) acc[i] = (f32x4){0.f, 0.f, 0.f, 0.f};
#pragma unroll
  for (int kst = 0; kst < 8; ++kst) {
    int k0 = kst * 32 + l4 * 8;
    bf16x8 a = ld8(xr + k0);
#pragma unroll
    for (int cs = 0; cs < 4; ++cs) {
      int col = col0 + cs * 16 + l15;
      bf16x8 bw = ld8(wqkvT + (size_t)col * 256 + k0);
      acc[cs] = MFMA16(a, bw, acc[cs]);
    }
  }
#pragma unroll
  for (int cs = 0; cs < 4; ++cs) {
    int col = col0 + cs * 16 + l15;
    float bias = bqkv[col];
    int which = col >> 8, c = col & 255;
    int h = c >> 6, hd = c & 63;
    float scale = (which == 0) ? SCLQ : 1.0f;
#pragma unroll
    for (int j = 0; j < 4; ++j) {
      int row = row0 + l4 * 4 + j;
      int bb = row >> 11, n = row & 2047;
      u16 val = f2bf((acc[cs][j] + bias) * scale);
      if (which == 2)
        Vtb[((size_t)((bb * Hh + h) * HD + hd)) * Nn + n] = val;
      else if (which == 0)
        Qb[(size_t)(((bb * Hh + h) * Nn + n)) * HD + hd] = val;
      else
        Kb[(size_t)(((bb * Hh + h) * Nn + n)) * HD + hd] = val;
    }
  }
}

// ================= attention: 8-wave k-split, 32-col tiles ================
// R15 structure; stores moved OUT of the PV loop into a dependency-free
// streaming epilogue (p regs stay live). Pass-2 FIFO is then [V(i),V(i+1)]
// only: vmcnt(4) steady state, vmcnt(0) tail.
__global__ __launch_bounds__(512, 4) void attn_kernel(
    const u16* Qb, const u16* Kb, const u16* Vtb, const u8* codes,
    const float* ee_g, float* attn_out, u16* ctx_ws) {
  __shared__ __align__(16) char smem[81920];

  int bid0 = blockIdx.x;
  int bid = ((bid0 & 7) << 8) | (bid0 >> 3);   // XCD-chunked (2048 % 8 == 0)
  int qt = bid & 127;
  int h = (bid >> 7) & 3;
  int b = bid >> 9;
  int w = threadIdx.x >> 6, lane = threadIdx.x & 63;
  int l15 = lane & 15, l4 = lane >> 4;
  int q0 = qt * 16;
  int bh = b * Hh + h;
  int wk0 = w * 256;                 // this wave's k-range start

  float* lsh = (float*)(smem + 65536);
  char* pwave = smem + 65536 + w * 2048;
  char* kv0 = smem + w * 8192;
  char* kv1 = kv0 + 4096;

  // 24-entry bias LUT (log2 domain, MSUB folded in), one value per lane 0..23
  float lutv = 0.f;
  {
    int ln = lane;
    int et = ln - 6 * (ln / 6);
    int tm = (ln / 6) & 1;
    int adj = ln / 12;
    if (ln < 24)
      lutv = (ee_g[et * Hh + h] + (tm ? 0.10f : -0.05f)) * LOG2E +
             (adj ? 0.f : -1.442695041e9f) - MSUB;
  }
  int lut_i = __float_as_int(lutv);

  // Q as B-fragment (pre-scaled by SCLQ in qkv_kernel)
  const u16* Qp = Qb + (size_t)(bh * Nn + q0 + l15) * HD;
  bf16x8 bq0 = ld8(Qp + l4 * 8);
  bf16x8 bq1 = ld8(Qp + 32 + l4 * 8);

  const char* Kg = (const char*)Kb + (size_t)bh * Nn * 128 + (size_t)wk0 * 128;
  const char* KgS[4];
  {
    int colK = ((lane & 7) * 16) ^ (((lane >> 3) & 7) << 4);
#pragma unroll
    for (int j = 0; j < 4; ++j)
      KgS[j] = Kg + (size_t)(j * 8 + (lane >> 3)) * 128 + colK;
  }
  const char* Vg = (const char*)Vtb + (size_t)bh * HD * Nn * 2 + (size_t)wk0 * 2;
  const char* VgS[4];
  {
    int sV = (((lane & 3) ^ (lane >> 4)) & 3) * 16;
#pragma unroll
    for (int j = 0; j < 4; ++j)
      VgS[j] = Vg + (size_t)(j * 16 + (lane >> 2)) * (Nn * 2) + sV;
  }

  const char* cpb = (const char*)codes + (size_t)(b * 128 + qt) * 32768 +
                    (size_t)(w * 4) * 1024 + lane * 16;

  int swK = (l15 & 7) << 4;
  int raK = (l15 * 128 + l4 * 16) ^ swK;
  int rv = l15 * 64 + ((l4 ^ ((l15 >> 2) & 3)) * 16);

  uint p[8][4];
  float accl = 0.f;

  // ---------- pass 1: QK^T + bias + exp2, once ----------
  u32x2 cw = *(const u32x2*)cpb;
#pragma unroll
  for (int j = 0; j < 4; ++j) stage16(KgS[j], kv0 + j * 1024);

#pragma unroll
  for (int i = 0; i < 8; ++i) {
    u32x2 cwn = cw;
    char* kcur = (i & 1) ? kv1 : kv0;
    char* knxt = (i & 1) ? kv0 : kv1;
    if (i < 7) {
      cwn = *(const u32x2*)(cpb + ((i + 1) >> 1) * 1024 + ((i + 1) & 1) * 8);
#pragma unroll
      for (int j = 0; j < 4; ++j)
        stage16(KgS[j] + (size_t)(i + 1) * 4096, knxt + j * 1024);
    }
    __builtin_amdgcn_sched_barrier(0);
    if (i < 7) asm volatile("s_waitcnt vmcnt(5) lgkmcnt(0)" ::: "memory");
    else       asm volatile("s_waitcnt vmcnt(0) lgkmcnt(0)" ::: "memory");
    __builtin_amdgcn_sched_barrier(0);
#pragma unroll
    for (int ks = 0; ks < 2; ++ks) {
      uint cword = cw[ks];
      f32x4 acc;
#pragma unroll
      for (int j = 0; j < 4; ++j)
        acc[j] = __int_as_float(
            __builtin_amdgcn_ds_bpermute((int)((cword >> (8 * j)) & 0xFFu), lut_i));
      acc = MFMA16(ld8((const u16*)(kcur + raK + ks * 2048)), bq0, acc);
      acc = MFMA16(ld8((const u16*)(kcur + (raK ^ 64) + ks * 2048)), bq1, acc);
      float e0 = __builtin_amdgcn_exp2f(acc[0]);
      float e1 = __builtin_amdgcn_exp2f(acc[1]);
      float e2 = __builtin_amdgcn_exp2f(acc[2]);
      float e3 = __builtin_amdgcn_exp2f(acc[3]);
      accl += (e0 + e1) + (e2 + e3);
      asm("v_cvt_pk_bf16_f32 %0, %1, %2" : "=v"(p[i][ks * 2]) : "v"(e0), "v"(e1));
      asm("v_cvt_pk_bf16_f32 %0, %1, %2" : "=v"(p[i][ks * 2 + 1]) : "v"(e2), "v"(e3));
    }
    cw = cwn;
  }
  accl += __shfl_xor(accl, 16);
  accl += __shfl_xor(accl, 32);
  if (lane < 16) lsh[w * 16 + lane] = accl;
  __syncthreads();
  float tot = 0.f;
#pragma unroll
  for (int ww = 0; ww < 8; ++ww) tot += lsh[ww * 16 + l15];
  bool zrow = (tot == 0.0f);
  float cscale = zrow ? (1.0f / 2048.0f) : (1.0f / tot);
  __syncthreads();   // lsh read done before P writes overwrite its region

  // ---------- pass 2: PV only (no QK recompute, no stores) ----------
  f32x4 ctx[4];
#pragma unroll
  for (int i = 0; i < 4; ++i) ctx[i] = (f32x4){0.f, 0.f, 0.f, 0.f};

#pragma unroll
  for (int j = 0; j < 4; ++j) stage16(VgS[j], kv0 + j * 1024);

#pragma unroll
  for (int i = 0; i < 8; ++i) {
    char* vcur = (i & 1) ? kv1 : kv0;
    char* vnxt = (i & 1) ? kv0 : kv1;
    if (i < 7) {
#pragma unroll
      for (int j = 0; j < 4; ++j)
        stage16(VgS[j] + (size_t)(i + 1) * 64, vnxt + j * 1024);
    }
    __builtin_amdgcn_sched_barrier(0);
    if (i < 7) asm volatile("s_waitcnt vmcnt(4) lgkmcnt(0)" ::: "memory");
    else       asm volatile("s_waitcnt vmcnt(0) lgkmcnt(0)" ::: "memory");
    __builtin_amdgcn_sched_barrier(0);

    uint pp[4];
#pragma unroll
    for (int r = 0; r < 4; ++r) pp[r] = zrow ? 0x3F803F80u : p[i][r];
    // P -> LDS (swizzled 64B rows)
#pragma unroll
    for (int ks = 0; ks < 2; ++ks) {
      int slot = (ks * 2 + (l4 >> 1)) ^ ((l15 >> 2) & 3);
      int2 wv = {(int)pp[ks * 2], (int)pp[ks * 2 + 1]};
      *(int2*)(pwave + l15 * 64 + slot * 16 + (l4 & 1) * 8) = wv;
    }
    // PV with unnormalized P
    bf16x8 pa = ld8((const u16*)(pwave + rv));
#pragma unroll
    for (int d = 0; d < 4; ++d) {
      bf16x8 v = ld8((const u16*)(vcur + d * 1024 + rv));
      ctx[d] = MFMA16(pa, v, ctx[d]);
    }
  }

  // ---------- attn store epilogue: pure streaming from registers ----------
  float* attb = attn_out + (size_t)bh * Nn * Nn + (size_t)(q0 + l15) * Nn + wk0;
#pragma unroll
  for (int i = 0; i < 8; ++i) {
#pragma unroll
    for (int ks = 0; ks < 2; ++ks) {
      uint u0 = zrow ? 0x3F803F80u : p[i][ks * 2];
      uint u1 = zrow ? 0x3F803F80u : p[i][ks * 2 + 1];
      f32x4 o;
      o[0] = __int_as_float((int)(u0 << 16)) * cscale;
      o[1] = __int_as_float((int)(u0 & 0xFFFF0000u)) * cscale;
      o[2] = __int_as_float((int)(u1 << 16)) * cscale;
      o[3] = __int_as_float((int)(u1 & 0xFFFF0000u)) * cscale;
      __builtin_nontemporal_store(o, (f32x4*)(attb + i * 32 + ks * 16 + l4 * 4));
    }
  }

  // per-row scale of partial ctx (rows = l4*4+j; cscale lives at lane==row)
  float csr[4];
#pragma unroll
  for (int j = 0; j < 4; ++j)
    csr[j] = __int_as_float(
        __builtin_amdgcn_ds_bpermute((l4 * 4 + j) * 4, __float_as_int(cscale)));
#pragma unroll
  for (int d = 0; d < 4; ++d)
#pragma unroll
    for (int j = 0; j < 4; ++j) ctx[d][j] *= csr[j];

  // combine partial ctx across the 8 k-split waves (reuse K/V region)
  __syncthreads();
  float* creg = (float*)smem;
  if (w > 0) {
    float* cs_ = creg + ((size_t)(w - 1) * 64 + lane) * 17;
#pragma unroll
    for (int d = 0; d < 4; ++d)
#pragma unroll
      for (int j = 0; j < 4; ++j) cs_[d * 4 + j] = ctx[d][j];
  }
  __syncthreads();
  if (w == 0) {
#pragma unroll
    for (int d = 0; d < 4; ++d) {
      int col = h * 64 + d * 16 + l15;
#pragma unroll
      for (int j = 0; j < 4; ++j) {
        float v = ctx[d][j];
#pragma unroll
        for (int ww = 0; ww < 7; ++ww)
          v += creg[((size_t)ww * 64 + lane) * 17 + d * 4 + j];
        int qrow = q0 + l4 * 4 + j;
        ctx_ws[(size_t)(b * Nn + qrow) * Dd + col] = f2bf(v);
      }
    }
  }
}

// ================= out GEMM + residual + LayerNorm =================
__global__ __launch_bounds__(256) void outln_kernel(const u16* ctxb, const u16* woT,
                                                    const float* bo, const float* xf,
                                                    const float* ln_g, const float* ln_b,
                                                    float* yout) {
  __shared__ float ytile[32][257];
  __shared__ float muS[32], rvS[32];
  int bm0 = blockIdx.x * 32;
  int w = threadIdx.x >> 6, lane = threadIdx.x & 63;
  int l15 = lane & 15, l4 = lane >> 4;
  f32x4 acc[2][4];
#pragma unroll
  for (int q = 0; q < 2; ++q)
#pragma unroll
    for (int i = 0; i < 4; ++i) acc[q][i] = (f32x4){0.f, 0.f, 0.f, 0.f};
#pragma unroll
  for (int kst = 0; kst < 8; ++kst) {
    int k0 = kst * 32 + l4 * 8;
    bf16x8 a0 = ld8(ctxb + (size_t)(bm0 + l15) * 256 + k0);
    bf16x8 a1 = ld8(ctxb + (size_t)(bm0 + 16 + l15) * 256 + k0);
#pragma unroll
    for (int ds_ = 0; ds_ < 4; ++ds_) {
      bf16x8 bw = ld8(woT + (size_t)(w * 64 + ds_ * 16 + l15) * 256 + k0);
      acc[0][ds_] = MFMA16(a0, bw, acc[0][ds_]);
      acc[1][ds_] = MFMA16(a1, bw, acc[1][ds_]);
    }
  }
#pragma unroll
  for (int qs = 0; qs < 2; ++qs)
#pragma unroll
    for (int ds_ = 0; ds_ < 4; ++ds_) {
      int col = w * 64 + ds_ * 16 + l15;
      float bof = bo[col];
#pragma unroll
      for (int j = 0; j < 4; ++j) {
        int row = qs * 16 + l4 * 4 + j;
        ytile[row][col] = acc[qs][ds_][j] + bof + xf[(size_t)(bm0 + row) * 256 + col];
      }
    }
  __syncthreads();
  int row = threadIdx.x >> 3, seg = threadIdx.x & 7;
  float ps = 0.f, pq = 0.f;
#pragma unroll
  for (int c = 0; c < 32; ++c) {
    float v = ytile[row][seg * 32 + c];
    ps += v; pq += v * v;
  }
  ps += __shfl_xor(ps, 1); pq += __shfl_xor(pq, 1);
  ps += __shfl_xor(ps, 2); pq += __shfl_xor(pq, 2);
  ps += __shfl_xor(ps, 4); pq += __shfl_xor(pq, 4);
  if (seg == 0) {
    float mu = ps * (1.0f / 256.0f);
    muS[row] = mu;
    rvS[row] = rsqrtf(pq * (1.0f / 256.0f) - mu * mu + 1e-5f);
  }
  __syncthreads();
  float mu = muS[row], rv = rvS[row];
  float* yr = yout + (size_t)(bm0 + row) * 256;
#pragma unroll
  for (int c0 = 0; c0 < 32; c0 += 4) {
    int c = seg * 32 + c0;
    float4 o;
    o.x = (ytile[row][c + 0] - mu) * rv * ln_g[c + 0] + ln_b[c + 0];
    o.y = (ytile[row][c + 1] - mu) * rv * ln_g[c + 1] + ln_b[c + 1];
    o.z = (ytile[row][c + 2] - mu) * rv * ln_g[c + 2] + ln_b[c + 2];
    o.w = (ytile[row][c + 3] - mu) * rv * ln_g[c + 3] + ln_b[c + 3];
    *(float4*)(yr + c) = o;
  }
}

extern "C" void kernel_launch(void* const* d_in, const int* in_sizes, int n_in,
                              void* d_out, int out_size, void* d_ws, size_t ws_size,
                              hipStream_t stream) {
  const float* nodes = (const float*)d_in[0];
  const int* node_types = (const int*)d_in[1];
  const int* edge_types = (const int*)d_in[2];
  const float* adjacency = (const float*)d_in[3];
  const float* nte = (const float*)d_in[4];
  const float* ee = (const float*)d_in[5];
  const float* Wq = (const float*)d_in[6];
  const float* bq = (const float*)d_in[7];
  const float* Wk = (const float*)d_in[8];
  const float* bk = (const float*)d_in[9];
  const float* Wv = (const float*)d_in[10];
  const float* bv = (const float*)d_in[11];
  const float* Wo = (const float*)d_in[12];
  const float* bo = (const float*)d_in[13];
  const float* ln_g = (const float*)d_in[14];
  const float* ln_b = (const float*)d_in[15];

  float* y = (float*)d_out;
  float* attn = y + (size_t)Bsz * Nn * Dd;

  char* ws = (char*)d_ws;
  float* xf = (float*)(ws + OFF_X);
  u16* xbf = (u16*)(ws + OFF_XBF);
  u16* wqkvT = (u16*)(ws + OFF_WQKVT);
  u16* woT = (u16*)(ws + OFF_WOT);
  float* bqkv = (float*)(ws + OFF_BQKV);
  u16* Qb = (u16*)(ws + OFF_Q);
  u16* Kb = (u16*)(ws + OFF_K);
  u16* Vtb = (u16*)(ws + OFF_VT);
  u16* ctxb = (u16*)(ws + OFF_CTX);
  u8* codes = (u8*)(ws + OFF_CODES);

  pack_kernel<<<1027, 256, 0, stream>>>(Wq, Wk, Wv, Wo, bq, bk, bv, wqkvT, woT, bqkv);
  embed_kernel<<<2048, 256, 0, stream>>>(nodes, node_types, nte, xf, xbf);
  maskpack_kernel<<<512, 256, 0, stream>>>(node_types, edge_types, adjacency, codes);
  qkv_kernel<<<dim3(12, 128), 256, 0, stream>>>(xbf, wqkvT, bqkv, Qb, Kb, Vtb);
  attn_kernel<<<2048, 512, 0, stream>>>(Qb, Kb, Vtb, codes, ee, attn, ctxb);
  outln_kernel<<<256, 256, 0, stream>>>(ctxb, woT, bo, xf, ln_g, ln_b, y);
}

// Round 18
// 175.327 us; speedup vs baseline: 1.1520x; 1.1264x over previous
//
#include <hip/hip_runtime.h>

#define Bsz 4
#define Nn 2048
#define Dd 256
#define Hh 4
#define HD 64
#define NTt 5
#define ETt 6
#define LOG2E 1.4426950408889634f
#define MSUB 24.0f
#define SCLQ 0.18033688011112042f   // 0.125 * LOG2E, folded into Q at qkv time

typedef float f32x4 __attribute__((ext_vector_type(4)));
typedef __bf16 bf16x8 __attribute__((ext_vector_type(8)));
typedef unsigned int u32x4 __attribute__((ext_vector_type(4)));
typedef unsigned int u32x2 __attribute__((ext_vector_type(2)));
typedef unsigned short u16;
typedef unsigned char u8;
typedef unsigned int uint;

static __device__ __forceinline__ u16 f2bf(float f) {
  unsigned int u = __builtin_bit_cast(unsigned int, f);
  u = (u + 0x7fffu + ((u >> 16) & 1u)) >> 16;
  return (u16)u;
}

static __device__ __forceinline__ bf16x8 ld8(const u16* p) {
  return __builtin_bit_cast(bf16x8, *(const u32x4*)p);
}

// async global->LDS, 16B per lane; LDS dest = wave-uniform base + lane*16
static __device__ __forceinline__ void stage16(const void* g, void* l) {
  __builtin_amdgcn_global_load_lds(
      (const __attribute__((address_space(1))) uint*)g,
      (__attribute__((address_space(3))) uint*)l, 16, 0, 0);
}

#define MFMA16(a, b, c) __builtin_amdgcn_mfma_f32_16x16x32_bf16((a), (b), (c), 0, 0, 0)

// ---------------- ws layout (bytes) ----------------
#define OFF_X      0u            // f32  [8192][256]        8388608
#define OFF_XBF    8388608u      // bf16 [8192][256]        4194304
#define OFF_WQKVT  12582912u     // bf16 [768][256]         393216
#define OFF_WOT    12976128u     // bf16 [256][256]         131072
#define OFF_BQKV   13107200u     // f32  [768]              3072
#define OFF_Q      13110272u     // bf16 [B,H,N,64]         4194304
#define OFF_K      17304576u     // bf16 [B,H,N,64]         4194304
#define OFF_VT     25693184u     // bf16 [B,H,64,N]         4194304
#define OFF_CTX    29887488u     // bf16 [8192][256]        4194304
#define OFF_CODES  34081792u     // u8   [B,128,32,64,16]   16777216

// ========== fused pack + embed (no LDS, independent streams) ==========
// blockIdx [0,2048): embed   [2048,3075): pack weights
__global__ void pe_kernel(const float* nodes, const int* node_types,
                          const float* nte,
                          const float* Wq, const float* Wk, const float* Wv,
                          const float* Wo, const float* bq, const float* bk,
                          const float* bv,
                          float* xf, u16* xbf, u16* wqkvT, u16* woT, float* bqkv) {
  int gb = blockIdx.x;
  if (gb < 2048) {
    int t = gb * 256 + threadIdx.x;          // 524288 threads, 4 floats each
    int flat = t * 4;
    int bn = flat >> 8, d0 = flat & 255;
    int nt = node_types[bn];
    float4 nv = *(const float4*)(nodes + flat);
    float4 ev = *(const float4*)(nte + nt * 256 + d0);
    float4 x4;
    x4.x = nv.x + ev.x; x4.y = nv.y + ev.y; x4.z = nv.z + ev.z; x4.w = nv.w + ev.w;
    *(float4*)(xf + flat) = x4;
    ushort4 xb;
    xb.x = f2bf(x4.x); xb.y = f2bf(x4.y); xb.z = f2bf(x4.z); xb.w = f2bf(x4.w);
    *(ushort4*)(xbf + flat) = xb;
  } else {
    int tid = (gb - 2048) * 256 + threadIdx.x;
    if (tid < 196608) {                 // WqkvT[c][k] = W_which[k][cc]
      int c = tid >> 8, k = tid & 255;
      int which = c >> 8, cc = c & 255;
      const float* W = (which == 0) ? Wq : ((which == 1) ? Wk : Wv);
      wqkvT[tid] = f2bf(W[k * 256 + cc]);
    } else if (tid < 262144) {          // WoT[c][k] = Wo[k][c]
      int t2 = tid - 196608;
      int c = t2 >> 8, k = t2 & 255;
      woT[t2] = f2bf(Wo[k * 256 + c]);
    } else if (tid < 262912) {
      int c = tid - 262144;
      int which = c >> 8, cc = c & 255;
      bqkv[c] = (which == 0) ? bq[cc] : ((which == 1) ? bk[cc] : bv[cc]);
    }
  }
}

// ================= mask pack v2: LDS-transposed, coalesced R/W ============
__global__ __launch_bounds__(256) void maskpack_kernel(
    const int* node_types, const int* edge_types, const float* adjacency,
    u8* codes) {
  __shared__ uint lw[16 * 516 + 4];          // padded stride 516 (33KB)
  int blk = blockIdx.x;                       // 0..511
  int qt = blk & 127;
  int b = blk >> 7;
  int t = threadIdx.x;
  const int* ntb = node_types + b * Nn;
  const int* etb = edge_types + (size_t)b * Nn * Nn + (size_t)qt * 16 * Nn;
  const float* adjb = adjacency + (size_t)b * Nn * Nn + (size_t)qt * 16 * Nn;

#pragma unroll 4
  for (int a = 0; a < 32; ++a) {
    int idx = a * 256 + t;                    // int4 index within (16 x 512)
    int row = idx >> 9;                       // 0..15
    int k4 = idx & 511;                       // int4 within row
    int k0 = k4 * 4;
    int ntq = ntb[qt * 16 + row];
    int4 et4 = *(const int4*)(etb + (size_t)row * Nn + k0);
    float4 a4 = *(const float4*)(adjb + (size_t)row * Nn + k0);
    int4 nt4 = *(const int4*)(ntb + k0);
    int e[4] = {et4.x, et4.y, et4.z, et4.w};
    int n[4] = {nt4.x, nt4.y, nt4.z, nt4.w};
    float av[4] = {a4.x, a4.y, a4.z, a4.w};
    uint word = 0;
#pragma unroll
    for (int j = 0; j < 4; ++j) {
      int code = e[j] + ((ntq == n[j]) ? 6 : 0) + ((av[j] != 0.0f) ? 12 : 0);
      word |= (uint)(code * 4) << (8 * j);
    }
    lw[row * 516 + k4] = word;
  }
  __syncthreads();

  u8* rec = codes + (size_t)(b * 128 + qt) * 32768;
#pragma unroll
  for (int c = 0; c < 8; ++c) {
    int W = (c * 256 + t) * 4;                // output word base (dwordx4)
    int kt = W >> 8;
    int rem = W & 255;
    int l4 = rem >> 6;
    int l15 = (rem >> 2) & 15;
    int base = l15 * 516 + kt * 16 + l4;      // + 4*s for s=0..3 (ks)
    u32x4 o = {lw[base], lw[base + 4], lw[base + 8], lw[base + 12]};
    *(u32x4*)(rec + (size_t)W * 4) = o;
  }
}

// ================= QKV GEMM: [8192,256] @ [256,768] =================
__global__ __launch_bounds__(256) void qkv_kernel(const u16* xbf, const u16* wqkvT,
                                                  const float* bqkv,
                                                  u16* Qb, u16* Kb, u16* Vtb) {
  int cb = blockIdx.x;              // 0..11
  int rb = blockIdx.y;              // 0..127
  int w = threadIdx.x >> 6, lane = threadIdx.x & 63;
  int l15 = lane & 15, l4 = lane >> 4;
  int row0 = rb * 64 + w * 16;
  int col0 = cb * 64;
  const u16* xr = xbf + (size_t)(row0 + l15) * 256;
  f32x4 acc[4];
#pragma unroll
  for (int i = 0; i < 4; ++i) acc[i] = (f32x4){0.f, 0.f, 0.f, 0.f};
#pragma unroll
  for (int kst = 0; kst < 8; ++kst) {
    int k0 = kst * 32 + l4 * 8;
    bf16x8 a = ld8(xr + k0);
#pragma unroll
    for (int cs = 0; cs < 4; ++cs) {
      int col = col0 + cs * 16 + l15;
      bf16x8 bw = ld8(wqkvT + (size_t)col * 256 + k0);
      acc[cs] = MFMA16(a, bw, acc[cs]);
    }
  }
#pragma unroll
  for (int cs = 0; cs < 4; ++cs) {
    int col = col0 + cs * 16 + l15;
    float bias = bqkv[col];
    int which = col >> 8, c = col & 255;
    int h = c >> 6, hd = c & 63;
    float scale = (which == 0) ? SCLQ : 1.0f;
#pragma unroll
    for (int j = 0; j < 4; ++j) {
      int row = row0 + l4 * 4 + j;
      int bb = row >> 11, n = row & 2047;
      u16 val = f2bf((acc[cs][j] + bias) * scale);
      if (which == 2)
        Vtb[((size_t)((bb * Hh + h) * HD + hd)) * Nn + n] = val;
      else if (which == 0)
        Qb[(size_t)(((bb * Hh + h) * Nn + n)) * HD + hd] = val;
      else
        Kb[(size_t)(((bb * Hh + h) * Nn + n)) * HD + hd] = val;
    }
  }
}

// ================= attention: 8-wave k-split, 32-col tiles (R15) ==========
__global__ __launch_bounds__(512, 4) void attn_kernel(
    const u16* Qb, const u16* Kb, const u16* Vtb, const u8* codes,
    const float* ee_g, float* attn_out, u16* ctx_ws) {
  __shared__ __align__(16) char smem[81920];

  int bid0 = blockIdx.x;
  int bid = ((bid0 & 7) << 8) | (bid0 >> 3);   // XCD-chunked (2048 % 8 == 0)
  int qt = bid & 127;
  int h = (bid >> 7) & 3;
  int b = bid >> 9;
  int w = threadIdx.x >> 6, lane = threadIdx.x & 63;
  int l15 = lane & 15, l4 = lane >> 4;
  int q0 = qt * 16;
  int bh = b * Hh + h;
  int wk0 = w * 256;                 // this wave's k-range start

  float* lsh = (float*)(smem + 65536);
  char* pwave = smem + 65536 + w * 2048;
  char* kv0 = smem + w * 8192;
  char* kv1 = kv0 + 4096;

  // 24-entry bias LUT (log2 domain, MSUB folded in), one value per lane 0..23
  float lutv = 0.f;
  {
    int ln = lane;
    int et = ln - 6 * (ln / 6);
    int tm = (ln / 6) & 1;
    int adj = ln / 12;
    if (ln < 24)
      lutv = (ee_g[et * Hh + h] + (tm ? 0.10f : -0.05f)) * LOG2E +
             (adj ? 0.f : -1.442695041e9f) - MSUB;
  }
  int lut_i = __float_as_int(lutv);

  // Q as B-fragment (pre-scaled by SCLQ in qkv_kernel)
  const u16* Qp = Qb + (size_t)(bh * Nn + q0 + l15) * HD;
  bf16x8 bq0 = ld8(Qp + l4 * 8);
  bf16x8 bq1 = ld8(Qp + 32 + l4 * 8);

  const char* Kg = (const char*)Kb + (size_t)bh * Nn * 128 + (size_t)wk0 * 128;
  const char* KgS[4];
  {
    int colK = ((lane & 7) * 16) ^ (((lane >> 3) & 7) << 4);
#pragma unroll
    for (int j = 0; j < 4; ++j)
      KgS[j] = Kg + (size_t)(j * 8 + (lane >> 3)) * 128 + colK;
  }
  const char* Vg = (const char*)Vtb + (size_t)bh * HD * Nn * 2 + (size_t)wk0 * 2;
  const char* VgS[4];
  {
    int sV = (((lane & 3) ^ (lane >> 4)) & 3) * 16;
#pragma unroll
    for (int j = 0; j < 4; ++j)
      VgS[j] = Vg + (size_t)(j * 16 + (lane >> 2)) * (Nn * 2) + sV;
  }

  const char* cpb = (const char*)codes + (size_t)(b * 128 + qt) * 32768 +
                    (size_t)(w * 4) * 1024 + lane * 16;

  int swK = (l15 & 7) << 4;
  int raK = (l15 * 128 + l4 * 16) ^ swK;
  int rv = l15 * 64 + ((l4 ^ ((l15 >> 2) & 3)) * 16);

  uint p[8][4];
  float accl = 0.f;

  // ---------- pass 1: QK^T + bias + exp2, once ----------
  u32x2 cw = *(const u32x2*)cpb;
#pragma unroll
  for (int j = 0; j < 4; ++j) stage16(KgS[j], kv0 + j * 1024);

#pragma unroll
  for (int i = 0; i < 8; ++i) {
    u32x2 cwn = cw;
    char* kcur = (i & 1) ? kv1 : kv0;
    char* knxt = (i & 1) ? kv0 : kv1;
    if (i < 7) {
      cwn = *(const u32x2*)(cpb + ((i + 1) >> 1) * 1024 + ((i + 1) & 1) * 8);
#pragma unroll
      for (int j = 0; j < 4; ++j)
        stage16(KgS[j] + (size_t)(i + 1) * 4096, knxt + j * 1024);
    }
    __builtin_amdgcn_sched_barrier(0);
    if (i < 7) asm volatile("s_waitcnt vmcnt(5) lgkmcnt(0)" ::: "memory");
    else       asm volatile("s_waitcnt vmcnt(0) lgkmcnt(0)" ::: "memory");
    __builtin_amdgcn_sched_barrier(0);
#pragma unroll
    for (int ks = 0; ks < 2; ++ks) {
      uint cword = cw[ks];
      f32x4 acc;
#pragma unroll
      for (int j = 0; j < 4; ++j)
        acc[j] = __int_as_float(
            __builtin_amdgcn_ds_bpermute((int)((cword >> (8 * j)) & 0xFFu), lut_i));
      acc = MFMA16(ld8((const u16*)(kcur + raK + ks * 2048)), bq0, acc);
      acc = MFMA16(ld8((const u16*)(kcur + (raK ^ 64) + ks * 2048)), bq1, acc);
      float e0 = __builtin_amdgcn_exp2f(acc[0]);
      float e1 = __builtin_amdgcn_exp2f(acc[1]);
      float e2 = __builtin_amdgcn_exp2f(acc[2]);
      float e3 = __builtin_amdgcn_exp2f(acc[3]);
      accl += (e0 + e1) + (e2 + e3);
      asm("v_cvt_pk_bf16_f32 %0, %1, %2" : "=v"(p[i][ks * 2]) : "v"(e0), "v"(e1));
      asm("v_cvt_pk_bf16_f32 %0, %1, %2" : "=v"(p[i][ks * 2 + 1]) : "v"(e2), "v"(e3));
    }
    cw = cwn;
  }
  accl += __shfl_xor(accl, 16);
  accl += __shfl_xor(accl, 32);
  if (lane < 16) lsh[w * 16 + lane] = accl;
  __syncthreads();
  float tot = 0.f;
#pragma unroll
  for (int ww = 0; ww < 8; ++ww) tot += lsh[ww * 16 + l15];
  bool zrow = (tot == 0.0f);
  float cscale = zrow ? (1.0f / 2048.0f) : (1.0f / tot);
  __syncthreads();   // lsh read done before P writes overwrite its region

  // ---------- pass 2: attn store + PV (no QK recompute) ----------
  f32x4 ctx[4];
#pragma unroll
  for (int i = 0; i < 4; ++i) ctx[i] = (f32x4){0.f, 0.f, 0.f, 0.f};
  float* attb = attn_out + (size_t)bh * Nn * Nn + (size_t)(q0 + l15) * Nn + wk0;

#pragma unroll
  for (int j = 0; j < 4; ++j) stage16(VgS[j], kv0 + j * 1024);

#pragma unroll
  for (int i = 0; i < 8; ++i) {
    char* vcur = (i & 1) ? kv1 : kv0;
    char* vnxt = (i & 1) ? kv0 : kv1;
    if (i < 7) {
#pragma unroll
      for (int j = 0; j < 4; ++j)
        stage16(VgS[j] + (size_t)(i + 1) * 64, vnxt + j * 1024);
    }
    __builtin_amdgcn_sched_barrier(0);
    if (i == 0)     asm volatile("s_waitcnt vmcnt(4) lgkmcnt(0)" ::: "memory");
    else if (i < 7) asm volatile("s_waitcnt vmcnt(6) lgkmcnt(0)" ::: "memory");
    else            asm volatile("s_waitcnt vmcnt(2) lgkmcnt(0)" ::: "memory");
    __builtin_amdgcn_sched_barrier(0);

    uint pp[4];
#pragma unroll
    for (int r = 0; r < 4; ++r) pp[r] = zrow ? 0x3F803F80u : p[i][r];
    // P -> LDS (swizzled 64B rows)
#pragma unroll
    for (int ks = 0; ks < 2; ++ks) {
      int slot = (ks * 2 + (l4 >> 1)) ^ ((l15 >> 2) & 3);
      int2 wv = {(int)pp[ks * 2], (int)pp[ks * 2 + 1]};
      *(int2*)(pwave + l15 * 64 + slot * 16 + (l4 & 1) * 8) = wv;
    }
    // attn output: float(p)*cscale
#pragma unroll
    for (int ks = 0; ks < 2; ++ks) {
      uint u0 = pp[ks * 2], u1 = pp[ks * 2 + 1];
      f32x4 o;
      o[0] = __int_as_float((int)(u0 << 16)) * cscale;
      o[1] = __int_as_float((int)(u0 & 0xFFFF0000u)) * cscale;
      o[2] = __int_as_float((int)(u1 << 16)) * cscale;
      o[3] = __int_as_float((int)(u1 & 0xFFFF0000u)) * cscale;
      __builtin_nontemporal_store(o, (f32x4*)(attb + i * 32 + ks * 16 + l4 * 4));
    }
    // PV with unnormalized P
    bf16x8 pa = ld8((const u16*)(pwave + rv));
#pragma unroll
    for (int d = 0; d < 4; ++d) {
      bf16x8 v = ld8((const u16*)(vcur + d * 1024 + rv));
      ctx[d] = MFMA16(pa, v, ctx[d]);
    }
  }

  // per-row scale of partial ctx (rows = l4*4+j; cscale lives at lane==row)
  float csr[4];
#pragma unroll
  for (int j = 0; j < 4; ++j)
    csr[j] = __int_as_float(
        __builtin_amdgcn_ds_bpermute((l4 * 4 + j) * 4, __float_as_int(cscale)));
#pragma unroll
  for (int d = 0; d < 4; ++d)
#pragma unroll
    for (int j = 0; j < 4; ++j) ctx[d][j] *= csr[j];

  // combine partial ctx across the 8 k-split waves (reuse K/V region)
  __syncthreads();
  float* creg = (float*)smem;
  if (w > 0) {
    float* cs_ = creg + ((size_t)(w - 1) * 64 + lane) * 17;
#pragma unroll
    for (int d = 0; d < 4; ++d)
#pragma unroll
      for (int j = 0; j < 4; ++j) cs_[d * 4 + j] = ctx[d][j];
  }
  __syncthreads();
  if (w == 0) {
#pragma unroll
    for (int d = 0; d < 4; ++d) {
      int col = h * 64 + d * 16 + l15;
#pragma unroll
      for (int j = 0; j < 4; ++j) {
        float v = ctx[d][j];
#pragma unroll
        for (int ww = 0; ww < 7; ++ww)
          v += creg[((size_t)ww * 64 + lane) * 17 + d * 4 + j];
        int qrow = q0 + l4 * 4 + j;
        ctx_ws[(size_t)(b * Nn + qrow) * Dd + col] = f2bf(v);
      }
    }
  }
}

// ================= out GEMM + residual + LayerNorm =================
__global__ __launch_bounds__(256) void outln_kernel(const u16* ctxb, const u16* woT,
                                                    const float* bo, const float* xf,
                                                    const float* ln_g, const float* ln_b,
                                                    float* yout) {
  __shared__ float ytile[32][257];
  __shared__ float muS[32], rvS[32];
  int bm0 = blockIdx.x * 32;
  int w = threadIdx.x >> 6, lane = threadIdx.x & 63;
  int l15 = lane & 15, l4 = lane >> 4;
  f32x4 acc[2][4];
#pragma unroll
  for (int q = 0; q < 2; ++q)
#pragma unroll
    for (int i = 0; i < 4; ++i) acc[q][i] = (f32x4){0.f, 0.f, 0.f, 0.f};
#pragma unroll
  for (int kst = 0; kst < 8; ++kst) {
    int k0 = kst * 32 + l4 * 8;
    bf16x8 a0 = ld8(ctxb + (size_t)(bm0 + l15) * 256 + k0);
    bf16x8 a1 = ld8(ctxb + (size_t)(bm0 + 16 + l15) * 256 + k0);
#pragma unroll
    for (int ds_ = 0; ds_ < 4; ++ds_) {
      bf16x8 bw = ld8(woT + (size_t)(w * 64 + ds_ * 16 + l15) * 256 + k0);
      acc[0][ds_] = MFMA16(a0, bw, acc[0][ds_]);
      acc[1][ds_] = MFMA16(a1, bw, acc[1][ds_]);
    }
  }
#pragma unroll
  for (int qs = 0; qs < 2; ++qs)
#pragma unroll
    for (int ds_ = 0; ds_ < 4; ++ds_) {
      int col = w * 64 + ds_ * 16 + l15;
      float bof = bo[col];
#pragma unroll
      for (int j = 0; j < 4; ++j) {
        int row = qs * 16 + l4 * 4 + j;
        ytile[row][col] = acc[qs][ds_][j] + bof + xf[(size_t)(bm0 + row) * 256 + col];
      }
    }
  __syncthreads();
  int row = threadIdx.x >> 3, seg = threadIdx.x & 7;
  float ps = 0.f, pq = 0.f;
#pragma unroll
  for (int c = 0; c < 32; ++c) {
    float v = ytile[row][seg * 32 + c];
    ps += v; pq += v * v;
  }
  ps += __shfl_xor(ps, 1); pq += __shfl_xor(pq, 1);
  ps += __shfl_xor(ps, 2); pq += __shfl_xor(pq, 2);
  ps += __shfl_xor(ps, 4); pq += __shfl_xor(pq, 4);
  if (seg == 0) {
    float mu = ps * (1.0f / 256.0f);
    muS[row] = mu;
    rvS[row] = rsqrtf(pq * (1.0f / 256.0f) - mu * mu + 1e-5f);
  }
  __syncthreads();
  float mu = muS[row], rv = rvS[row];
  float* yr = yout + (size_t)(bm0 + row) * 256;
#pragma unroll
  for (int c0 = 0; c0 < 32; c0 += 4) {
    int c = seg * 32 + c0;
    float4 o;
    o.x = (ytile[row][c + 0] - mu) * rv * ln_g[c + 0] + ln_b[c + 0];
    o.y = (ytile[row][c + 1] - mu) * rv * ln_g[c + 1] + ln_b[c + 1];
    o.z = (ytile[row][c + 2] - mu) * rv * ln_g[c + 2] + ln_b[c + 2];
    o.w = (ytile[row][c + 3] - mu) * rv * ln_g[c + 3] + ln_b[c + 3];
    *(float4*)(yr + c) = o;
  }
}

extern "C" void kernel_launch(void* const* d_in, const int* in_sizes, int n_in,
                              void* d_out, int out_size, void* d_ws, size_t ws_size,
                              hipStream_t stream) {
  const float* nodes = (const float*)d_in[0];
  const int* node_types = (const int*)d_in[1];
  const int* edge_types = (const int*)d_in[2];
  const float* adjacency = (const float*)d_in[3];
  const float* nte = (const float*)d_in[4];
  const float* ee = (const float*)d_in[5];
  const float* Wq = (const float*)d_in[6];
  const float* bq = (const float*)d_in[7];
  const float* Wk = (const float*)d_in[8];
  const float* bk = (const float*)d_in[9];
  const float* Wv = (const float*)d_in[10];
  const float* bv = (const float*)d_in[11];
  const float* Wo = (const float*)d_in[12];
  const float* bo = (const float*)d_in[13];
  const float* ln_g = (const float*)d_in[14];
  const float* ln_b = (const float*)d_in[15];

  float* y = (float*)d_out;
  float* attn = y + (size_t)Bsz * Nn * Dd;

  char* ws = (char*)d_ws;
  float* xf = (float*)(ws + OFF_X);
  u16* xbf = (u16*)(ws + OFF_XBF);
  u16* wqkvT = (u16*)(ws + OFF_WQKVT);
  u16* woT = (u16*)(ws + OFF_WOT);
  float* bqkv = (float*)(ws + OFF_BQKV);
  u16* Qb = (u16*)(ws + OFF_Q);
  u16* Kb = (u16*)(ws + OFF_K);
  u16* Vtb = (u16*)(ws + OFF_VT);
  u16* ctxb = (u16*)(ws + OFF_CTX);
  u8* codes = (u8*)(ws + OFF_CODES);

  pe_kernel<<<3075, 256, 0, stream>>>(nodes, node_types, nte, Wq, Wk, Wv, Wo,
                                      bq, bk, bv, xf, xbf, wqkvT, woT, bqkv);
  maskpack_kernel<<<512, 256, 0, stream>>>(node_types, edge_types, adjacency, codes);
  qkv_kernel<<<dim3(12, 128), 256, 0, stream>>>(xbf, wqkvT, bqkv, Qb, Kb, Vtb);
  attn_kernel<<<2048, 512, 0, stream>>>(Qb, Kb, Vtb, codes, ee, attn, ctxb);
  outln_kernel<<<256, 256, 0, stream>>>(ctxb, woT, bo, xf, ln_g, ln_b, y);
}

// Round 19
// 173.383 us; speedup vs baseline: 1.1650x; 1.0112x over previous
//
#include <hip/hip_runtime.h>

#define Bsz 4
#define Nn 2048
#define Dd 256
#define Hh 4
#define HD 64
#define NTt 5
#define ETt 6
#define LOG2E 1.4426950408889634f
#define MSUB 24.0f
#define SCLQ 0.18033688011112042f   // 0.125 * LOG2E, folded into Q at qkv time

typedef float f32x4 __attribute__((ext_vector_type(4)));
typedef __bf16 bf16x8 __attribute__((ext_vector_type(8)));
typedef unsigned int u32x4 __attribute__((ext_vector_type(4)));
typedef unsigned int u32x2 __attribute__((ext_vector_type(2)));
typedef unsigned short u16;
typedef unsigned char u8;
typedef unsigned int uint;

static __device__ __forceinline__ u16 f2bf(float f) {
  unsigned int u = __builtin_bit_cast(unsigned int, f);
  u = (u + 0x7fffu + ((u >> 16) & 1u)) >> 16;
  return (u16)u;
}

static __device__ __forceinline__ bf16x8 ld8(const u16* p) {
  return __builtin_bit_cast(bf16x8, *(const u32x4*)p);
}

// async global->LDS, 16B per lane; LDS dest = wave-uniform base + lane*16
static __device__ __forceinline__ void stage16(const void* g, void* l) {
  __builtin_amdgcn_global_load_lds(
      (const __attribute__((address_space(1))) uint*)g,
      (__attribute__((address_space(3))) uint*)l, 16, 0, 0);
}

#define MFMA16(a, b, c) __builtin_amdgcn_mfma_f32_16x16x32_bf16((a), (b), (c), 0, 0, 0)

// ---------------- ws layout (bytes) ----------------
#define OFF_X      0u            // f32  [8192][256]        8388608
#define OFF_XBF    8388608u      // bf16 [8192][256]        4194304
#define OFF_WQKVT  12582912u     // bf16 [768][256]         393216
#define OFF_WOT    12976128u     // bf16 [256][256]         131072
#define OFF_BQKV   13107200u     // f32  [768]              3072
#define OFF_Q      13110272u     // bf16 [B,H,N,64]         4194304
#define OFF_K      17304576u     // bf16 [B,H,N,64]         4194304
#define OFF_VT     25693184u     // bf16 [B,H,64,N]         4194304
#define OFF_CTX    29887488u     // bf16 [8192][256]        4194304
#define OFF_CODES  34081792u     // u8   [B,128,32,64,16]   16777216

// ========== fused pack + embed (no LDS, independent streams) ==========
// blockIdx [0,2048): embed   [2048,3075): pack weights
__global__ void pe_kernel(const float* nodes, const int* node_types,
                          const float* nte,
                          const float* Wq, const float* Wk, const float* Wv,
                          const float* Wo, const float* bq, const float* bk,
                          const float* bv,
                          float* xf, u16* xbf, u16* wqkvT, u16* woT, float* bqkv) {
  int gb = blockIdx.x;
  if (gb < 2048) {
    int t = gb * 256 + threadIdx.x;          // 524288 threads, 4 floats each
    int flat = t * 4;
    int bn = flat >> 8, d0 = flat & 255;
    int nt = node_types[bn];
    float4 nv = *(const float4*)(nodes + flat);
    float4 ev = *(const float4*)(nte + nt * 256 + d0);
    float4 x4;
    x4.x = nv.x + ev.x; x4.y = nv.y + ev.y; x4.z = nv.z + ev.z; x4.w = nv.w + ev.w;
    *(float4*)(xf + flat) = x4;
    ushort4 xb;
    xb.x = f2bf(x4.x); xb.y = f2bf(x4.y); xb.z = f2bf(x4.z); xb.w = f2bf(x4.w);
    *(ushort4*)(xbf + flat) = xb;
  } else {
    int tid = (gb - 2048) * 256 + threadIdx.x;
    if (tid < 196608) {                 // WqkvT[c][k] = W_which[k][cc]
      int c = tid >> 8, k = tid & 255;
      int which = c >> 8, cc = c & 255;
      const float* W = (which == 0) ? Wq : ((which == 1) ? Wk : Wv);
      wqkvT[tid] = f2bf(W[k * 256 + cc]);
    } else if (tid < 262144) {          // WoT[c][k] = Wo[k][c]
      int t2 = tid - 196608;
      int c = t2 >> 8, k = t2 & 255;
      woT[t2] = f2bf(Wo[k * 256 + c]);
    } else if (tid < 262912) {
      int c = tid - 262144;
      int which = c >> 8, cc = c & 255;
      bqkv[c] = (which == 0) ? bq[cc] : ((which == 1) ? bk[cc] : bv[cc]);
    }
  }
}

// ================= mask pack v2: LDS-transposed, coalesced R/W ============
__global__ __launch_bounds__(256) void maskpack_kernel(
    const int* node_types, const int* edge_types, const float* adjacency,
    u8* codes) {
  __shared__ uint lw[16 * 516 + 4];          // padded stride 516 (33KB)
  int blk = blockIdx.x;                       // 0..511
  int qt = blk & 127;
  int b = blk >> 7;
  int t = threadIdx.x;
  const int* ntb = node_types + b * Nn;
  const int* etb = edge_types + (size_t)b * Nn * Nn + (size_t)qt * 16 * Nn;
  const float* adjb = adjacency + (size_t)b * Nn * Nn + (size_t)qt * 16 * Nn;

#pragma unroll 4
  for (int a = 0; a < 32; ++a) {
    int idx = a * 256 + t;                    // int4 index within (16 x 512)
    int row = idx >> 9;                       // 0..15
    int k4 = idx & 511;                       // int4 within row
    int k0 = k4 * 4;
    int ntq = ntb[qt * 16 + row];
    int4 et4 = *(const int4*)(etb + (size_t)row * Nn + k0);
    float4 a4 = *(const float4*)(adjb + (size_t)row * Nn + k0);
    int4 nt4 = *(const int4*)(ntb + k0);
    int e[4] = {et4.x, et4.y, et4.z, et4.w};
    int n[4] = {nt4.x, nt4.y, nt4.z, nt4.w};
    float av[4] = {a4.x, a4.y, a4.z, a4.w};
    uint word = 0;
#pragma unroll
    for (int j = 0; j < 4; ++j) {
      int code = e[j] + ((ntq == n[j]) ? 6 : 0) + ((av[j] != 0.0f) ? 12 : 0);
      word |= (uint)(code * 4) << (8 * j);
    }
    lw[row * 516 + k4] = word;
  }
  __syncthreads();

  u8* rec = codes + (size_t)(b * 128 + qt) * 32768;
#pragma unroll
  for (int c = 0; c < 8; ++c) {
    int W = (c * 256 + t) * 4;                // output word base (dwordx4)
    int kt = W >> 8;
    int rem = W & 255;
    int l4 = rem >> 6;
    int l15 = (rem >> 2) & 15;
    int base = l15 * 516 + kt * 16 + l4;      // + 4*s for s=0..3 (ks)
    u32x4 o = {lw[base], lw[base + 4], lw[base + 8], lw[base + 12]};
    *(u32x4*)(rec + (size_t)W * 4) = o;
  }
}

// ================= QKV GEMM: [8192,256] @ [256,768] =================
__global__ __launch_bounds__(256) void qkv_kernel(const u16* xbf, const u16* wqkvT,
                                                  const float* bqkv,
                                                  u16* Qb, u16* Kb, u16* Vtb) {
  int cb = blockIdx.x;              // 0..11
  int rb = blockIdx.y;              // 0..127
  int w = threadIdx.x >> 6, lane = threadIdx.x & 63;
  int l15 = lane & 15, l4 = lane >> 4;
  int row0 = rb * 64 + w * 16;
  int col0 = cb * 64;
  const u16* xr = xbf + (size_t)(row0 + l15) * 256;
  f32x4 acc[4];
#pragma unroll
  for (int i = 0; i < 4; ++i) acc[i] = (f32x4){0.f, 0.f, 0.f, 0.f};
#pragma unroll
  for (int kst = 0; kst < 8; ++kst) {
    int k0 = kst * 32 + l4 * 8;
    bf16x8 a = ld8(xr + k0);
#pragma unroll
    for (int cs = 0; cs < 4; ++cs) {
      int col = col0 + cs * 16 + l15;
      bf16x8 bw = ld8(wqkvT + (size_t)col * 256 + k0);
      acc[cs] = MFMA16(a, bw, acc[cs]);
    }
  }
#pragma unroll
  for (int cs = 0; cs < 4; ++cs) {
    int col = col0 + cs * 16 + l15;
    float bias = bqkv[col];
    int which = col >> 8, c = col & 255;
    int h = c >> 6, hd = c & 63;
    float scale = (which == 0) ? SCLQ : 1.0f;
#pragma unroll
    for (int j = 0; j < 4; ++j) {
      int row = row0 + l4 * 4 + j;
      int bb = row >> 11, n = row & 2047;
      u16 val = f2bf((acc[cs][j] + bias) * scale);
      if (which == 2)
        Vtb[((size_t)((bb * Hh + h) * HD + hd)) * Nn + n] = val;
      else if (which == 0)
        Qb[(size_t)(((bb * Hh + h) * Nn + n)) * HD + hd] = val;
      else
        Kb[(size_t)(((bb * Hh + h) * Nn + n)) * HD + hd] = val;
    }
  }
}

// ================= attention: 8-wave k-split, 32-col tiles ================
// R18 structure + codes HOISTED: all 8 u32x2 code loads issue at kernel
// entry into registers (cwa[8], statically indexed) and drain once under the
// first vmcnt — removing an L3/HBM-latency load from the per-iteration FIFO
// (prefetch distance was only 1 iteration). Pass-1 wait is uniform vmcnt(4).
__global__ __launch_bounds__(512, 4) void attn_kernel(
    const u16* Qb, const u16* Kb, const u16* Vtb, const u8* codes,
    const float* ee_g, float* attn_out, u16* ctx_ws) {
  __shared__ __align__(16) char smem[81920];

  int bid0 = blockIdx.x;
  int bid = ((bid0 & 7) << 8) | (bid0 >> 3);   // XCD-chunked (2048 % 8 == 0)
  int qt = bid & 127;
  int h = (bid >> 7) & 3;
  int b = bid >> 9;
  int w = threadIdx.x >> 6, lane = threadIdx.x & 63;
  int l15 = lane & 15, l4 = lane >> 4;
  int q0 = qt * 16;
  int bh = b * Hh + h;
  int wk0 = w * 256;                 // this wave's k-range start

  float* lsh = (float*)(smem + 65536);
  char* pwave = smem + 65536 + w * 2048;
  char* kv0 = smem + w * 8192;
  char* kv1 = kv0 + 4096;

  // 24-entry bias LUT (log2 domain, MSUB folded in), one value per lane 0..23
  float lutv = 0.f;
  {
    int ln = lane;
    int et = ln - 6 * (ln / 6);
    int tm = (ln / 6) & 1;
    int adj = ln / 12;
    if (ln < 24)
      lutv = (ee_g[et * Hh + h] + (tm ? 0.10f : -0.05f)) * LOG2E +
             (adj ? 0.f : -1.442695041e9f) - MSUB;
  }
  int lut_i = __float_as_int(lutv);

  // Q as B-fragment (pre-scaled by SCLQ in qkv_kernel)
  const u16* Qp = Qb + (size_t)(bh * Nn + q0 + l15) * HD;
  bf16x8 bq0 = ld8(Qp + l4 * 8);
  bf16x8 bq1 = ld8(Qp + 32 + l4 * 8);

  const char* Kg = (const char*)Kb + (size_t)bh * Nn * 128 + (size_t)wk0 * 128;
  const char* KgS[4];
  {
    int colK = ((lane & 7) * 16) ^ (((lane >> 3) & 7) << 4);
#pragma unroll
    for (int j = 0; j < 4; ++j)
      KgS[j] = Kg + (size_t)(j * 8 + (lane >> 3)) * 128 + colK;
  }
  const char* Vg = (const char*)Vtb + (size_t)bh * HD * Nn * 2 + (size_t)wk0 * 2;
  const char* VgS[4];
  {
    int sV = (((lane & 3) ^ (lane >> 4)) & 3) * 16;
#pragma unroll
    for (int j = 0; j < 4; ++j)
      VgS[j] = Vg + (size_t)(j * 16 + (lane >> 2)) * (Nn * 2) + sV;
  }

  const char* cpb = (const char*)codes + (size_t)(b * 128 + qt) * 32768 +
                    (size_t)(w * 4) * 1024 + lane * 16;

  int swK = (l15 & 7) << 4;
  int raK = (l15 * 128 + l4 * 16) ^ swK;
  int rv = l15 * 64 + ((l4 ^ ((l15 >> 2) & 3)) * 16);

  uint p[8][4];
  float accl = 0.f;

  // ---------- hoisted codes loads: 8 x u32x2 into registers ----------
  u32x2 cwa[8];
#pragma unroll
  for (int i = 0; i < 8; ++i)
    cwa[i] = *(const u32x2*)(cpb + (i >> 1) * 1024 + (i & 1) * 8);

  // ---------- pass 1: QK^T + bias + exp2, once ----------
#pragma unroll
  for (int j = 0; j < 4; ++j) stage16(KgS[j], kv0 + j * 1024);

#pragma unroll
  for (int i = 0; i < 8; ++i) {
    char* kcur = (i & 1) ? kv1 : kv0;
    char* knxt = (i & 1) ? kv0 : kv1;
    if (i < 7) {
#pragma unroll
      for (int j = 0; j < 4; ++j)
        stage16(KgS[j] + (size_t)(i + 1) * 4096, knxt + j * 1024);
    }
    __builtin_amdgcn_sched_barrier(0);
    if (i < 7) asm volatile("s_waitcnt vmcnt(4) lgkmcnt(0)" ::: "memory");
    else       asm volatile("s_waitcnt vmcnt(0) lgkmcnt(0)" ::: "memory");
    __builtin_amdgcn_sched_barrier(0);
#pragma unroll
    for (int ks = 0; ks < 2; ++ks) {
      uint cword = cwa[i][ks];
      f32x4 acc;
#pragma unroll
      for (int j = 0; j < 4; ++j)
        acc[j] = __int_as_float(
            __builtin_amdgcn_ds_bpermute((int)((cword >> (8 * j)) & 0xFFu), lut_i));
      acc = MFMA16(ld8((const u16*)(kcur + raK + ks * 2048)), bq0, acc);
      acc = MFMA16(ld8((const u16*)(kcur + (raK ^ 64) + ks * 2048)), bq1, acc);
      float e0 = __builtin_amdgcn_exp2f(acc[0]);
      float e1 = __builtin_amdgcn_exp2f(acc[1]);
      float e2 = __builtin_amdgcn_exp2f(acc[2]);
      float e3 = __builtin_amdgcn_exp2f(acc[3]);
      accl += (e0 + e1) + (e2 + e3);
      asm("v_cvt_pk_bf16_f32 %0, %1, %2" : "=v"(p[i][ks * 2]) : "v"(e0), "v"(e1));
      asm("v_cvt_pk_bf16_f32 %0, %1, %2" : "=v"(p[i][ks * 2 + 1]) : "v"(e2), "v"(e3));
    }
  }
  accl += __shfl_xor(accl, 16);
  accl += __shfl_xor(accl, 32);
  if (lane < 16) lsh[w * 16 + lane] = accl;
  __syncthreads();
  float tot = 0.f;
#pragma unroll
  for (int ww = 0; ww < 8; ++ww) tot += lsh[ww * 16 + l15];
  bool zrow = (tot == 0.0f);
  float cscale = zrow ? (1.0f / 2048.0f) : (1.0f / tot);
  __syncthreads();   // lsh read done before P writes overwrite its region

  // ---------- pass 2: attn store + PV (no QK recompute) ----------
  f32x4 ctx[4];
#pragma unroll
  for (int i = 0; i < 4; ++i) ctx[i] = (f32x4){0.f, 0.f, 0.f, 0.f};
  float* attb = attn_out + (size_t)bh * Nn * Nn + (size_t)(q0 + l15) * Nn + wk0;

#pragma unroll
  for (int j = 0; j < 4; ++j) stage16(VgS[j], kv0 + j * 1024);

#pragma unroll
  for (int i = 0; i < 8; ++i) {
    char* vcur = (i & 1) ? kv1 : kv0;
    char* vnxt = (i & 1) ? kv0 : kv1;
    if (i < 7) {
#pragma unroll
      for (int j = 0; j < 4; ++j)
        stage16(VgS[j] + (size_t)(i + 1) * 64, vnxt + j * 1024);
    }
    __builtin_amdgcn_sched_barrier(0);
    if (i == 0)     asm volatile("s_waitcnt vmcnt(4) lgkmcnt(0)" ::: "memory");
    else if (i < 7) asm volatile("s_waitcnt vmcnt(6) lgkmcnt(0)" ::: "memory");
    else            asm volatile("s_waitcnt vmcnt(2) lgkmcnt(0)" ::: "memory");
    __builtin_amdgcn_sched_barrier(0);

    uint pp[4];
#pragma unroll
    for (int r = 0; r < 4; ++r) pp[r] = zrow ? 0x3F803F80u : p[i][r];
    // P -> LDS (swizzled 64B rows)
#pragma unroll
    for (int ks = 0; ks < 2; ++ks) {
      int slot = (ks * 2 + (l4 >> 1)) ^ ((l15 >> 2) & 3);
      int2 wv = {(int)pp[ks * 2], (int)pp[ks * 2 + 1]};
      *(int2*)(pwave + l15 * 64 + slot * 16 + (l4 & 1) * 8) = wv;
    }
    // attn output: float(p)*cscale
#pragma unroll
    for (int ks = 0; ks < 2; ++ks) {
      uint u0 = pp[ks * 2], u1 = pp[ks * 2 + 1];
      f32x4 o;
      o[0] = __int_as_float((int)(u0 << 16)) * cscale;
      o[1] = __int_as_float((int)(u0 & 0xFFFF0000u)) * cscale;
      o[2] = __int_as_float((int)(u1 << 16)) * cscale;
      o[3] = __int_as_float((int)(u1 & 0xFFFF0000u)) * cscale;
      __builtin_nontemporal_store(o, (f32x4*)(attb + i * 32 + ks * 16 + l4 * 4));
    }
    // PV with unnormalized P
    bf16x8 pa = ld8((const u16*)(pwave + rv));
#pragma unroll
    for (int d = 0; d < 4; ++d) {
      bf16x8 v = ld8((const u16*)(vcur + d * 1024 + rv));
      ctx[d] = MFMA16(pa, v, ctx[d]);
    }
  }

  // per-row scale of partial ctx (rows = l4*4+j; cscale lives at lane==row)
  float csr[4];
#pragma unroll
  for (int j = 0; j < 4; ++j)
    csr[j] = __int_as_float(
        __builtin_amdgcn_ds_bpermute((l4 * 4 + j) * 4, __float_as_int(cscale)));
#pragma unroll
  for (int d = 0; d < 4; ++d)
#pragma unroll
    for (int j = 0; j < 4; ++j) ctx[d][j] *= csr[j];

  // combine partial ctx across the 8 k-split waves (reuse K/V region)
  __syncthreads();
  float* creg = (float*)smem;
  if (w > 0) {
    float* cs_ = creg + ((size_t)(w - 1) * 64 + lane) * 17;
#pragma unroll
    for (int d = 0; d < 4; ++d)
#pragma unroll
      for (int j = 0; j < 4; ++j) cs_[d * 4 + j] = ctx[d][j];
  }
  __syncthreads();
  if (w == 0) {
#pragma unroll
    for (int d = 0; d < 4; ++d) {
      int col = h * 64 + d * 16 + l15;
#pragma unroll
      for (int j = 0; j < 4; ++j) {
        float v = ctx[d][j];
#pragma unroll
        for (int ww = 0; ww < 7; ++ww)
          v += creg[((size_t)ww * 64 + lane) * 17 + d * 4 + j];
        int qrow = q0 + l4 * 4 + j;
        ctx_ws[(size_t)(b * Nn + qrow) * Dd + col] = f2bf(v);
      }
    }
  }
}

// ================= out GEMM + residual + LayerNorm =================
__global__ __launch_bounds__(256) void outln_kernel(const u16* ctxb, const u16* woT,
                                                    const float* bo, const float* xf,
                                                    const float* ln_g, const float* ln_b,
                                                    float* yout) {
  __shared__ float ytile[32][257];
  __shared__ float muS[32], rvS[32];
  int bm0 = blockIdx.x * 32;
  int w = threadIdx.x >> 6, lane = threadIdx.x & 63;
  int l15 = lane & 15, l4 = lane >> 4;
  f32x4 acc[2][4];
#pragma unroll
  for (int q = 0; q < 2; ++q)
#pragma unroll
    for (int i = 0; i < 4; ++i) acc[q][i] = (f32x4){0.f, 0.f, 0.f, 0.f};
#pragma unroll
  for (int kst = 0; kst < 8; ++kst) {
    int k0 = kst * 32 + l4 * 8;
    bf16x8 a0 = ld8(ctxb + (size_t)(bm0 + l15) * 256 + k0);
    bf16x8 a1 = ld8(ctxb + (size_t)(bm0 + 16 + l15) * 256 + k0);
#pragma unroll
    for (int ds_ = 0; ds_ < 4; ++ds_) {
      bf16x8 bw = ld8(woT + (size_t)(w * 64 + ds_ * 16 + l15) * 256 + k0);
      acc[0][ds_] = MFMA16(a0, bw, acc[0][ds_]);
      acc[1][ds_] = MFMA16(a1, bw, acc[1][ds_]);
    }
  }
#pragma unroll
  for (int qs = 0; qs < 2; ++qs)
#pragma unroll
    for (int ds_ = 0; ds_ < 4; ++ds_) {
      int col = w * 64 + ds_ * 16 + l15;
      float bof = bo[col];
#pragma unroll
      for (int j = 0; j < 4; ++j) {
        int row = qs * 16 + l4 * 4 + j;
        ytile[row][col] = acc[qs][ds_][j] + bof + xf[(size_t)(bm0 + row) * 256 + col];
      }
    }
  __syncthreads();
  int row = threadIdx.x >> 3, seg = threadIdx.x & 7;
  float ps = 0.f, pq = 0.f;
#pragma unroll
  for (int c = 0; c < 32; ++c) {
    float v = ytile[row][seg * 32 + c];
    ps += v; pq += v * v;
  }
  ps += __shfl_xor(ps, 1); pq += __shfl_xor(pq, 1);
  ps += __shfl_xor(ps, 2); pq += __shfl_xor(pq, 2);
  ps += __shfl_xor(ps, 4); pq += __shfl_xor(pq, 4);
  if (seg == 0) {
    float mu = ps * (1.0f / 256.0f);
    muS[row] = mu;
    rvS[row] = rsqrtf(pq * (1.0f / 256.0f) - mu * mu + 1e-5f);
  }
  __syncthreads();
  float mu = muS[row], rv = rvS[row];
  float* yr = yout + (size_t)(bm0 + row) * 256;
#pragma unroll
  for (int c0 = 0; c0 < 32; c0 += 4) {
    int c = seg * 32 + c0;
    float4 o;
    o.x = (ytile[row][c + 0] - mu) * rv * ln_g[c + 0] + ln_b[c + 0];
    o.y = (ytile[row][c + 1] - mu) * rv * ln_g[c + 1] + ln_b[c + 1];
    o.z = (ytile[row][c + 2] - mu) * rv * ln_g[c + 2] + ln_b[c + 2];
    o.w = (ytile[row][c + 3] - mu) * rv * ln_g[c + 3] + ln_b[c + 3];
    *(float4*)(yr + c) = o;
  }
}

extern "C" void kernel_launch(void* const* d_in, const int* in_sizes, int n_in,
                              void* d_out, int out_size, void* d_ws, size_t ws_size,
                              hipStream_t stream) {
  const float* nodes = (const float*)d_in[0];
  const int* node_types = (const int*)d_in[1];
  const int* edge_types = (const int*)d_in[2];
  const float* adjacency = (const float*)d_in[3];
  const float* nte = (const float*)d_in[4];
  const float* ee = (const float*)d_in[5];
  const float* Wq = (const float*)d_in[6];
  const float* bq = (const float*)d_in[7];
  const float* Wk = (const float*)d_in[8];
  const float* bk = (const float*)d_in[9];
  const float* Wv = (const float*)d_in[10];
  const float* bv = (const float*)d_in[11];
  const float* Wo = (const float*)d_in[12];
  const float* bo = (const float*)d_in[13];
  const float* ln_g = (const float*)d_in[14];
  const float* ln_b = (const float*)d_in[15];

  float* y = (float*)d_out;
  float* attn = y + (size_t)Bsz * Nn * Dd;

  char* ws = (char*)d_ws;
  float* xf = (float*)(ws + OFF_X);
  u16* xbf = (u16*)(ws + OFF_XBF);
  u16* wqkvT = (u16*)(ws + OFF_WQKVT);
  u16* woT = (u16*)(ws + OFF_WOT);
  float* bqkv = (float*)(ws + OFF_BQKV);
  u16* Qb = (u16*)(ws + OFF_Q);
  u16* Kb = (u16*)(ws + OFF_K);
  u16* Vtb = (u16*)(ws + OFF_VT);
  u16* ctxb = (u16*)(ws + OFF_CTX);
  u8* codes = (u8*)(ws + OFF_CODES);

  pe_kernel<<<3075, 256, 0, stream>>>(nodes, node_types, nte, Wq, Wk, Wv, Wo,
                                      bq, bk, bv, xf, xbf, wqkvT, woT, bqkv);
  maskpack_kernel<<<512, 256, 0, stream>>>(node_types, edge_types, adjacency, codes);
  qkv_kernel<<<dim3(12, 128), 256, 0, stream>>>(xbf, wqkvT, bqkv, Qb, Kb, Vtb);
  attn_kernel<<<2048, 512, 0, stream>>>(Qb, Kb, Vtb, codes, ee, attn, ctxb);
  outln_kernel<<<256, 256, 0, stream>>>(ctxb, woT, bo, xf, ln_g, ln_b, y);
}

// Round 20
// 173.233 us; speedup vs baseline: 1.1660x; 1.0009x over previous
//
#include <hip/hip_runtime.h>

#define Bsz 4
#define Nn 2048
#define Dd 256
#define Hh 4
#define HD 64
#define NTt 5
#define ETt 6
#define LOG2E 1.4426950408889634f
#define MSUB 24.0f
#define SCLQ 0.18033688011112042f   // 0.125 * LOG2E, folded into Q at qkv time

typedef float f32x4 __attribute__((ext_vector_type(4)));
typedef __bf16 bf16x8 __attribute__((ext_vector_type(8)));
typedef unsigned int u32x4 __attribute__((ext_vector_type(4)));
typedef unsigned int u32x2 __attribute__((ext_vector_type(2)));
typedef unsigned short u16;
typedef unsigned char u8;
typedef unsigned int uint;

static __device__ __forceinline__ u16 f2bf(float f) {
  unsigned int u = __builtin_bit_cast(unsigned int, f);
  u = (u + 0x7fffu + ((u >> 16) & 1u)) >> 16;
  return (u16)u;
}

static __device__ __forceinline__ bf16x8 ld8(const u16* p) {
  return __builtin_bit_cast(bf16x8, *(const u32x4*)p);
}

// async global->LDS, 16B per lane; LDS dest = wave-uniform base + lane*16
static __device__ __forceinline__ void stage16(const void* g, void* l) {
  __builtin_amdgcn_global_load_lds(
      (const __attribute__((address_space(1))) uint*)g,
      (__attribute__((address_space(3))) uint*)l, 16, 0, 0);
}

#define MFMA16(a, b, c) __builtin_amdgcn_mfma_f32_16x16x32_bf16((a), (b), (c), 0, 0, 0)

// ---------------- ws layout (bytes) ----------------
#define OFF_X      0u            // f32  [8192][256]        8388608
#define OFF_XBF    8388608u      // bf16 [8192][256]        4194304
#define OFF_WQKVT  12582912u     // bf16 [768][256]         393216
#define OFF_WOT    12976128u     // bf16 [256][256]         131072
#define OFF_BQKV   13107200u     // f32  [768]              3072
#define OFF_Q      13110272u     // bf16 [B,H,N,64]         4194304
#define OFF_K      17304576u     // bf16 [B,H,N,64]         4194304
#define OFF_VT     25693184u     // bf16 [B,H,64,N]         4194304
#define OFF_CTX    29887488u     // bf16 [8192][256]        4194304
#define OFF_CODES  34081792u     // u8   [B,128,32,64,16]   16777216

// ========== fused pack + embed (no LDS, independent streams) ==========
// blockIdx [0,2048): embed   [2048,3075): pack weights
__global__ void pe_kernel(const float* nodes, const int* node_types,
                          const float* nte,
                          const float* Wq, const float* Wk, const float* Wv,
                          const float* Wo, const float* bq, const float* bk,
                          const float* bv,
                          float* xf, u16* xbf, u16* wqkvT, u16* woT, float* bqkv) {
  int gb = blockIdx.x;
  if (gb < 2048) {
    int t = gb * 256 + threadIdx.x;          // 524288 threads, 4 floats each
    int flat = t * 4;
    int bn = flat >> 8, d0 = flat & 255;
    int nt = node_types[bn];
    float4 nv = *(const float4*)(nodes + flat);
    float4 ev = *(const float4*)(nte + nt * 256 + d0);
    float4 x4;
    x4.x = nv.x + ev.x; x4.y = nv.y + ev.y; x4.z = nv.z + ev.z; x4.w = nv.w + ev.w;
    *(float4*)(xf + flat) = x4;
    ushort4 xb;
    xb.x = f2bf(x4.x); xb.y = f2bf(x4.y); xb.z = f2bf(x4.z); xb.w = f2bf(x4.w);
    *(ushort4*)(xbf + flat) = xb;
  } else {
    int tid = (gb - 2048) * 256 + threadIdx.x;
    if (tid < 196608) {                 // WqkvT[c][k] = W_which[k][cc]
      int c = tid >> 8, k = tid & 255;
      int which = c >> 8, cc = c & 255;
      const float* W = (which == 0) ? Wq : ((which == 1) ? Wk : Wv);
      wqkvT[tid] = f2bf(W[k * 256 + cc]);
    } else if (tid < 262144) {          // WoT[c][k] = Wo[k][c]
      int t2 = tid - 196608;
      int c = t2 >> 8, k = t2 & 255;
      woT[t2] = f2bf(Wo[k * 256 + c]);
    } else if (tid < 262912) {
      int c = tid - 262144;
      int which = c >> 8, cc = c & 255;
      bqkv[c] = (which == 0) ? bq[cc] : ((which == 1) ? bk[cc] : bv[cc]);
    }
  }
}

// ================= mask pack v2: LDS-transposed, coalesced R/W ============
__global__ __launch_bounds__(256) void maskpack_kernel(
    const int* node_types, const int* edge_types, const float* adjacency,
    u8* codes) {
  __shared__ uint lw[16 * 516 + 4];          // padded stride 516 (33KB)
  int blk = blockIdx.x;                       // 0..511
  int qt = blk & 127;
  int b = blk >> 7;
  int t = threadIdx.x;
  const int* ntb = node_types + b * Nn;
  const int* etb = edge_types + (size_t)b * Nn * Nn + (size_t)qt * 16 * Nn;
  const float* adjb = adjacency + (size_t)b * Nn * Nn + (size_t)qt * 16 * Nn;

#pragma unroll 4
  for (int a = 0; a < 32; ++a) {
    int idx = a * 256 + t;                    // int4 index within (16 x 512)
    int row = idx >> 9;                       // 0..15
    int k4 = idx & 511;                       // int4 within row
    int k0 = k4 * 4;
    int ntq = ntb[qt * 16 + row];
    int4 et4 = *(const int4*)(etb + (size_t)row * Nn + k0);
    float4 a4 = *(const float4*)(adjb + (size_t)row * Nn + k0);
    int4 nt4 = *(const int4*)(ntb + k0);
    int e[4] = {et4.x, et4.y, et4.z, et4.w};
    int n[4] = {nt4.x, nt4.y, nt4.z, nt4.w};
    float av[4] = {a4.x, a4.y, a4.z, a4.w};
    uint word = 0;
#pragma unroll
    for (int j = 0; j < 4; ++j) {
      int code = e[j] + ((ntq == n[j]) ? 6 : 0) + ((av[j] != 0.0f) ? 12 : 0);
      word |= (uint)(code * 4) << (8 * j);
    }
    lw[row * 516 + k4] = word;
  }
  __syncthreads();

  u8* rec = codes + (size_t)(b * 128 + qt) * 32768;
#pragma unroll
  for (int c = 0; c < 8; ++c) {
    int W = (c * 256 + t) * 4;                // output word base (dwordx4)
    int kt = W >> 8;
    int rem = W & 255;
    int l4 = rem >> 6;
    int l15 = (rem >> 2) & 15;
    int base = l15 * 516 + kt * 16 + l4;      // + 4*s for s=0..3 (ks)
    u32x4 o = {lw[base], lw[base + 4], lw[base + 8], lw[base + 12]};
    *(u32x4*)(rec + (size_t)W * 4) = o;
  }
}

// ================= QKV GEMM: [8192,256] @ [256,768] =================
__global__ __launch_bounds__(256) void qkv_kernel(const u16* xbf, const u16* wqkvT,
                                                  const float* bqkv,
                                                  u16* Qb, u16* Kb, u16* Vtb) {
  int cb = blockIdx.x;              // 0..11
  int rb = blockIdx.y;              // 0..127
  int w = threadIdx.x >> 6, lane = threadIdx.x & 63;
  int l15 = lane & 15, l4 = lane >> 4;
  int row0 = rb * 64 + w * 16;
  int col0 = cb * 64;
  const u16* xr = xbf + (size_t)(row0 + l15) * 256;
  f32x4 acc[4];
#pragma unroll
  for (int i = 0; i < 4; ++i) acc[i] = (f32x4){0.f, 0.f, 0.f, 0.f};
#pragma unroll
  for (int kst = 0; kst < 8; ++kst) {
    int k0 = kst * 32 + l4 * 8;
    bf16x8 a = ld8(xr + k0);
#pragma unroll
    for (int cs = 0; cs < 4; ++cs) {
      int col = col0 + cs * 16 + l15;
      bf16x8 bw = ld8(wqkvT + (size_t)col * 256 + k0);
      acc[cs] = MFMA16(a, bw, acc[cs]);
    }
  }
#pragma unroll
  for (int cs = 0; cs < 4; ++cs) {
    int col = col0 + cs * 16 + l15;
    float bias = bqkv[col];
    int which = col >> 8, c = col & 255;
    int h = c >> 6, hd = c & 63;
    float scale = (which == 0) ? SCLQ : 1.0f;
#pragma unroll
    for (int j = 0; j < 4; ++j) {
      int row = row0 + l4 * 4 + j;
      int bb = row >> 11, n = row & 2047;
      u16 val = f2bf((acc[cs][j] + bias) * scale);
      if (which == 2)
        Vtb[((size_t)((bb * Hh + h) * HD + hd)) * Nn + n] = val;
      else if (which == 0)
        Qb[(size_t)(((bb * Hh + h) * Nn + n)) * HD + hd] = val;
      else
        Kb[(size_t)(((bb * Hh + h) * Nn + n)) * HD + hd] = val;
    }
  }
}

// ================= attention: 8-wave k-split, 32-col tiles ================
// R19 structure (hoisted codes) + V(0) PRE-STAGED during pass-1's final
// iteration (kv0 is free there; i=7's vmcnt(0) drains it) so pass 2 opens
// with V(0) resident and no serial V-latency between the barriers.
__global__ __launch_bounds__(512, 4) void attn_kernel(
    const u16* Qb, const u16* Kb, const u16* Vtb, const u8* codes,
    const float* ee_g, float* attn_out, u16* ctx_ws) {
  __shared__ __align__(16) char smem[81920];

  int bid0 = blockIdx.x;
  int bid = ((bid0 & 7) << 8) | (bid0 >> 3);   // XCD-chunked (2048 % 8 == 0)
  int qt = bid & 127;
  int h = (bid >> 7) & 3;
  int b = bid >> 9;
  int w = threadIdx.x >> 6, lane = threadIdx.x & 63;
  int l15 = lane & 15, l4 = lane >> 4;
  int q0 = qt * 16;
  int bh = b * Hh + h;
  int wk0 = w * 256;                 // this wave's k-range start

  float* lsh = (float*)(smem + 65536);
  char* pwave = smem + 65536 + w * 2048;
  char* kv0 = smem + w * 8192;
  char* kv1 = kv0 + 4096;

  // 24-entry bias LUT (log2 domain, MSUB folded in), one value per lane 0..23
  float lutv = 0.f;
  {
    int ln = lane;
    int et = ln - 6 * (ln / 6);
    int tm = (ln / 6) & 1;
    int adj = ln / 12;
    if (ln < 24)
      lutv = (ee_g[et * Hh + h] + (tm ? 0.10f : -0.05f)) * LOG2E +
             (adj ? 0.f : -1.442695041e9f) - MSUB;
  }
  int lut_i = __float_as_int(lutv);

  // Q as B-fragment (pre-scaled by SCLQ in qkv_kernel)
  const u16* Qp = Qb + (size_t)(bh * Nn + q0 + l15) * HD;
  bf16x8 bq0 = ld8(Qp + l4 * 8);
  bf16x8 bq1 = ld8(Qp + 32 + l4 * 8);

  const char* Kg = (const char*)Kb + (size_t)bh * Nn * 128 + (size_t)wk0 * 128;
  const char* KgS[4];
  {
    int colK = ((lane & 7) * 16) ^ (((lane >> 3) & 7) << 4);
#pragma unroll
    for (int j = 0; j < 4; ++j)
      KgS[j] = Kg + (size_t)(j * 8 + (lane >> 3)) * 128 + colK;
  }
  const char* Vg = (const char*)Vtb + (size_t)bh * HD * Nn * 2 + (size_t)wk0 * 2;
  const char* VgS[4];
  {
    int sV = (((lane & 3) ^ (lane >> 4)) & 3) * 16;
#pragma unroll
    for (int j = 0; j < 4; ++j)
      VgS[j] = Vg + (size_t)(j * 16 + (lane >> 2)) * (Nn * 2) + sV;
  }

  const char* cpb = (const char*)codes + (size_t)(b * 128 + qt) * 32768 +
                    (size_t)(w * 4) * 1024 + lane * 16;

  int swK = (l15 & 7) << 4;
  int raK = (l15 * 128 + l4 * 16) ^ swK;
  int rv = l15 * 64 + ((l4 ^ ((l15 >> 2) & 3)) * 16);

  uint p[8][4];
  float accl = 0.f;

  // ---------- hoisted codes loads: 8 x u32x2 into registers ----------
  u32x2 cwa[8];
#pragma unroll
  for (int i = 0; i < 8; ++i)
    cwa[i] = *(const u32x2*)(cpb + (i >> 1) * 1024 + (i & 1) * 8);

  // ---------- pass 1: QK^T + bias + exp2, once ----------
#pragma unroll
  for (int j = 0; j < 4; ++j) stage16(KgS[j], kv0 + j * 1024);

#pragma unroll
  for (int i = 0; i < 8; ++i) {
    char* kcur = (i & 1) ? kv1 : kv0;
    char* knxt = (i & 1) ? kv0 : kv1;
    if (i < 7) {
#pragma unroll
      for (int j = 0; j < 4; ++j)
        stage16(KgS[j] + (size_t)(i + 1) * 4096, knxt + j * 1024);
    } else {
      // kv0 is free during i=7 (kcur = kv1): pre-stage V(0) for pass 2;
      // the vmcnt(0) below drains it together with K(7).
#pragma unroll
      for (int j = 0; j < 4; ++j) stage16(VgS[j], kv0 + j * 1024);
    }
    __builtin_amdgcn_sched_barrier(0);
    if (i < 7) asm volatile("s_waitcnt vmcnt(4) lgkmcnt(0)" ::: "memory");
    else       asm volatile("s_waitcnt vmcnt(0) lgkmcnt(0)" ::: "memory");
    __builtin_amdgcn_sched_barrier(0);
#pragma unroll
    for (int ks = 0; ks < 2; ++ks) {
      uint cword = cwa[i][ks];
      f32x4 acc;
#pragma unroll
      for (int j = 0; j < 4; ++j)
        acc[j] = __int_as_float(
            __builtin_amdgcn_ds_bpermute((int)((cword >> (8 * j)) & 0xFFu), lut_i));
      acc = MFMA16(ld8((const u16*)(kcur + raK + ks * 2048)), bq0, acc);
      acc = MFMA16(ld8((const u16*)(kcur + (raK ^ 64) + ks * 2048)), bq1, acc);
      float e0 = __builtin_amdgcn_exp2f(acc[0]);
      float e1 = __builtin_amdgcn_exp2f(acc[1]);
      float e2 = __builtin_amdgcn_exp2f(acc[2]);
      float e3 = __builtin_amdgcn_exp2f(acc[3]);
      accl += (e0 + e1) + (e2 + e3);
      asm("v_cvt_pk_bf16_f32 %0, %1, %2" : "=v"(p[i][ks * 2]) : "v"(e0), "v"(e1));
      asm("v_cvt_pk_bf16_f32 %0, %1, %2" : "=v"(p[i][ks * 2 + 1]) : "v"(e2), "v"(e3));
    }
  }
  accl += __shfl_xor(accl, 16);
  accl += __shfl_xor(accl, 32);
  if (lane < 16) lsh[w * 16 + lane] = accl;
  __syncthreads();
  float tot = 0.f;
#pragma unroll
  for (int ww = 0; ww < 8; ++ww) tot += lsh[ww * 16 + l15];
  bool zrow = (tot == 0.0f);
  float cscale = zrow ? (1.0f / 2048.0f) : (1.0f / tot);
  __syncthreads();   // lsh read done before P writes overwrite its region

  // ---------- pass 2: attn store + PV (V(0) already resident) ----------
  f32x4 ctx[4];
#pragma unroll
  for (int i = 0; i < 4; ++i) ctx[i] = (f32x4){0.f, 0.f, 0.f, 0.f};
  float* attb = attn_out + (size_t)bh * Nn * Nn + (size_t)(q0 + l15) * Nn + wk0;

#pragma unroll
  for (int i = 0; i < 8; ++i) {
    char* vcur = (i & 1) ? kv1 : kv0;
    char* vnxt = (i & 1) ? kv0 : kv1;
    if (i < 7) {
#pragma unroll
      for (int j = 0; j < 4; ++j)
        stage16(VgS[j] + (size_t)(i + 1) * 64, vnxt + j * 1024);
    }
    __builtin_amdgcn_sched_barrier(0);
    if (i == 0)     asm volatile("s_waitcnt vmcnt(4) lgkmcnt(0)" ::: "memory");
    else if (i < 7) asm volatile("s_waitcnt vmcnt(6) lgkmcnt(0)" ::: "memory");
    else            asm volatile("s_waitcnt vmcnt(2) lgkmcnt(0)" ::: "memory");
    __builtin_amdgcn_sched_barrier(0);

    uint pp[4];
#pragma unroll
    for (int r = 0; r < 4; ++r) pp[r] = zrow ? 0x3F803F80u : p[i][r];
    // P -> LDS (swizzled 64B rows)
#pragma unroll
    for (int ks = 0; ks < 2; ++ks) {
      int slot = (ks * 2 + (l4 >> 1)) ^ ((l15 >> 2) & 3);
      int2 wv = {(int)pp[ks * 2], (int)pp[ks * 2 + 1]};
      *(int2*)(pwave + l15 * 64 + slot * 16 + (l4 & 1) * 8) = wv;
    }
    // attn output: float(p)*cscale
#pragma unroll
    for (int ks = 0; ks < 2; ++ks) {
      uint u0 = pp[ks * 2], u1 = pp[ks * 2 + 1];
      f32x4 o;
      o[0] = __int_as_float((int)(u0 << 16)) * cscale;
      o[1] = __int_as_float((int)(u0 & 0xFFFF0000u)) * cscale;
      o[2] = __int_as_float((int)(u1 << 16)) * cscale;
      o[3] = __int_as_float((int)(u1 & 0xFFFF0000u)) * cscale;
      __builtin_nontemporal_store(o, (f32x4*)(attb + i * 32 + ks * 16 + l4 * 4));
    }
    // PV with unnormalized P
    bf16x8 pa = ld8((const u16*)(pwave + rv));
#pragma unroll
    for (int d = 0; d < 4; ++d) {
      bf16x8 v = ld8((const u16*)(vcur + d * 1024 + rv));
      ctx[d] = MFMA16(pa, v, ctx[d]);
    }
  }

  // per-row scale of partial ctx (rows = l4*4+j; cscale lives at lane==row)
  float csr[4];
#pragma unroll
  for (int j = 0; j < 4; ++j)
    csr[j] = __int_as_float(
        __builtin_amdgcn_ds_bpermute((l4 * 4 + j) * 4, __float_as_int(cscale)));
#pragma unroll
  for (int d = 0; d < 4; ++d)
#pragma unroll
    for (int j = 0; j < 4; ++j) ctx[d][j] *= csr[j];

  // combine partial ctx across the 8 k-split waves (reuse K/V region)
  __syncthreads();
  float* creg = (float*)smem;
  if (w > 0) {
    float* cs_ = creg + ((size_t)(w - 1) * 64 + lane) * 17;
#pragma unroll
    for (int d = 0; d < 4; ++d)
#pragma unroll
      for (int j = 0; j < 4; ++j) cs_[d * 4 + j] = ctx[d][j];
  }
  __syncthreads();
  if (w == 0) {
#pragma unroll
    for (int d = 0; d < 4; ++d) {
      int col = h * 64 + d * 16 + l15;
#pragma unroll
      for (int j = 0; j < 4; ++j) {
        float v = ctx[d][j];
#pragma unroll
        for (int ww = 0; ww < 7; ++ww)
          v += creg[((size_t)ww * 64 + lane) * 17 + d * 4 + j];
        int qrow = q0 + l4 * 4 + j;
        ctx_ws[(size_t)(b * Nn + qrow) * Dd + col] = f2bf(v);
      }
    }
  }
}

// ================= out GEMM + residual + LayerNorm =================
__global__ __launch_bounds__(256) void outln_kernel(const u16* ctxb, const u16* woT,
                                                    const float* bo, const float* xf,
                                                    const float* ln_g, const float* ln_b,
                                                    float* yout) {
  __shared__ float ytile[32][257];
  __shared__ float muS[32], rvS[32];
  int bm0 = blockIdx.x * 32;
  int w = threadIdx.x >> 6, lane = threadIdx.x & 63;
  int l15 = lane & 15, l4 = lane >> 4;
  f32x4 acc[2][4];
#pragma unroll
  for (int q = 0; q < 2; ++q)
#pragma unroll
    for (int i = 0; i < 4; ++i) acc[q][i] = (f32x4){0.f, 0.f, 0.f, 0.f};
#pragma unroll
  for (int kst = 0; kst < 8; ++kst) {
    int k0 = kst * 32 + l4 * 8;
    bf16x8 a0 = ld8(ctxb + (size_t)(bm0 + l15) * 256 + k0);
    bf16x8 a1 = ld8(ctxb + (size_t)(bm0 + 16 + l15) * 256 + k0);
#pragma unroll
    for (int ds_ = 0; ds_ < 4; ++ds_) {
      bf16x8 bw = ld8(woT + (size_t)(w * 64 + ds_ * 16 + l15) * 256 + k0);
      acc[0][ds_] = MFMA16(a0, bw, acc[0][ds_]);
      acc[1][ds_] = MFMA16(a1, bw, acc[1][ds_]);
    }
  }
#pragma unroll
  for (int qs = 0; qs < 2; ++qs)
#pragma unroll
    for (int ds_ = 0; ds_ < 4; ++ds_) {
      int col = w * 64 + ds_ * 16 + l15;
      float bof = bo[col];
#pragma unroll
      for (int j = 0; j < 4; ++j) {
        int row = qs * 16 + l4 * 4 + j;
        ytile[row][col] = acc[qs][ds_][j] + bof + xf[(size_t)(bm0 + row) * 256 + col];
      }
    }
  __syncthreads();
  int row = threadIdx.x >> 3, seg = threadIdx.x & 7;
  float ps = 0.f, pq = 0.f;
#pragma unroll
  for (int c = 0; c < 32; ++c) {
    float v = ytile[row][seg * 32 + c];
    ps += v; pq += v * v;
  }
  ps += __shfl_xor(ps, 1); pq += __shfl_xor(pq, 1);
  ps += __shfl_xor(ps, 2); pq += __shfl_xor(pq, 2);
  ps += __shfl_xor(ps, 4); pq += __shfl_xor(pq, 4);
  if (seg == 0) {
    float mu = ps * (1.0f / 256.0f);
    muS[row] = mu;
    rvS[row] = rsqrtf(pq * (1.0f / 256.0f) - mu * mu + 1e-5f);
  }
  __syncthreads();
  float mu = muS[row], rv = rvS[row];
  float* yr = yout + (size_t)(bm0 + row) * 256;
#pragma unroll
  for (int c0 = 0; c0 < 32; c0 += 4) {
    int c = seg * 32 + c0;
    float4 o;
    o.x = (ytile[row][c + 0] - mu) * rv * ln_g[c + 0] + ln_b[c + 0];
    o.y = (ytile[row][c + 1] - mu) * rv * ln_g[c + 1] + ln_b[c + 1];
    o.z = (ytile[row][c + 2] - mu) * rv * ln_g[c + 2] + ln_b[c + 2];
    o.w = (ytile[row][c + 3] - mu) * rv * ln_g[c + 3] + ln_b[c + 3];
    *(float4*)(yr + c) = o;
  }
}

extern "C" void kernel_launch(void* const* d_in, const int* in_sizes, int n_in,
                              void* d_out, int out_size, void* d_ws, size_t ws_size,
                              hipStream_t stream) {
  const float* nodes = (const float*)d_in[0];
  const int* node_types = (const int*)d_in[1];
  const int* edge_types = (const int*)d_in[2];
  const float* adjacency = (const float*)d_in[3];
  const float* nte = (const float*)d_in[4];
  const float* ee = (const float*)d_in[5];
  const float* Wq = (const float*)d_in[6];
  const float* bq = (const float*)d_in[7];
  const float* Wk = (const float*)d_in[8];
  const float* bk = (const float*)d_in[9];
  const float* Wv = (const float*)d_in[10];
  const float* bv = (const float*)d_in[11];
  const float* Wo = (const float*)d_in[12];
  const float* bo = (const float*)d_in[13];
  const float* ln_g = (const float*)d_in[14];
  const float* ln_b = (const float*)d_in[15];

  float* y = (float*)d_out;
  float* attn = y + (size_t)Bsz * Nn * Dd;

  char* ws = (char*)d_ws;
  float* xf = (float*)(ws + OFF_X);
  u16* xbf = (u16*)(ws + OFF_XBF);
  u16* wqkvT = (u16*)(ws + OFF_WQKVT);
  u16* woT = (u16*)(ws + OFF_WOT);
  float* bqkv = (float*)(ws + OFF_BQKV);
  u16* Qb = (u16*)(ws + OFF_Q);
  u16* Kb = (u16*)(ws + OFF_K);
  u16* Vtb = (u16*)(ws + OFF_VT);
  u16* ctxb = (u16*)(ws + OFF_CTX);
  u8* codes = (u8*)(ws + OFF_CODES);

  pe_kernel<<<3075, 256, 0, stream>>>(nodes, node_types, nte, Wq, Wk, Wv, Wo,
                                      bq, bk, bv, xf, xbf, wqkvT, woT, bqkv);
  maskpack_kernel<<<512, 256, 0, stream>>>(node_types, edge_types, adjacency, codes);
  qkv_kernel<<<dim3(12, 128), 256, 0, stream>>>(xbf, wqkvT, bqkv, Qb, Kb, Vtb);
  attn_kernel<<<2048, 512, 0, stream>>>(Qb, Kb, Vtb, codes, ee, attn, ctxb);
  outln_kernel<<<256, 256, 0, stream>>>(ctxb, woT, bo, xf, ln_g, ln_b, y);
}